// Round 1
// baseline (557.695 us; speedup 1.0000x reference)
//
#include <hip/hip_runtime.h>
#include <hip/hip_bf16.h>

// DeformableAttention3D — MI355X (gfx950)
// R8 = R7 (passing, 555 us) with k_fused restructured:
//   * pack phase: 128 threads precompute per-(h,l,p) sample indices+weights
//     once (was recomputed identically by all 32 threads of each head)
//   * divides eliminated: (rp + off/fW)*fW - 0.5  ==  rp*fW + off - 0.5
//     (exact: fW is a power of two)
//   * gather loop: int32 pre-scaled indices (LDS int4/float4 broadcast),
//     4 coalesced loads + 4 fma per point
//   * attn GEMV split across all 256 threads (K-halves), was t<128 only
// k_vgemv8 / detect / fallback path verbatim from R7.
#define EMBED    256
#define HEADS    8
#define LEVELS   4
#define POINTS   4
#define BATCH    2
#define M_TOT    21760   // 128*128 + 64*64 + 32*32 + 16*16

typedef __hip_bfloat16 bf16;
typedef __attribute__((ext_vector_type(8))) short short8;

__device__ __constant__ int c_H[LEVELS]  = {128, 64, 32, 16};
__device__ __constant__ int c_St[LEVELS] = {0, 16384, 20480, 21504};

template<bool BF>
__device__ __forceinline__ float ldf(const void* p, size_t i) {
  if (BF) return __bfloat162float(((const bf16*)p)[i]);
  else    return ((const float*)p)[i];
}
__device__ __forceinline__ float vt2f(float x) { return x; }
__device__ __forceinline__ float vt2f(bf16 x)  { return __bfloat162float(x); }

// ---------------------------------------------------------------------------
// Dtype detector (flag=1 -> buffers bf16, flag=0 -> f32). Verbatim R2/R6.
// ---------------------------------------------------------------------------
__global__ __launch_bounds__(256)
void k_detect(const unsigned short* __restrict__ q16, int* __restrict__ flag) {
  __shared__ int cnt;
  if (threadIdx.x == 0) cnt = 0;
  __syncthreads();
  int c = 0;
  for (int i = threadIdx.x; i < 8192; i += 256) {
    unsigned short v = q16[i];
    if ((v & 0x7F80u) == 0x7F80u) ++c;   // bf16 Inf/NaN pattern
  }
  if (c) atomicAdd(&cnt, c);
  __syncthreads();
  if (threadIdx.x == 0) flag[0] = (cnt == 0) ? 1 : 0;
}

// ---------------------------------------------------------------------------
// PROVEN (R6): 8-rows-per-block LDS-staged GEMV, N = 256 columns fixed.
// C[M x 256] = A[M x 256] @ W[256 x 256] + bias, f32 out.
// Used for BOTH value->v and query->off.
// ---------------------------------------------------------------------------
template<bool BF>
__device__ void vgemv8_body(const void* __restrict__ A, const void* __restrict__ W,
                            const void* __restrict__ bias, float* __restrict__ C,
                            int M) {
  const int t  = threadIdx.x;            // 256 threads
  const int r0 = blockIdx.x * 8;
  if (r0 >= M) return;

  __shared__ float rowA[8][EMBED];
  {
    int r  = t >> 5;                     // 0..7
    int rr = min(r0 + r, M - 1);         // clamp reads; stores guarded
    int c0 = (t & 31) * 8;               // 0..248
    if (BF) {
      const bf16* ap = (const bf16*)A + (size_t)rr * EMBED + c0;
      short8 a = *(const short8*)ap;
#pragma unroll
      for (int j = 0; j < 8; ++j) {
        short s = a[j];
        bf16 hb = *reinterpret_cast<bf16*>(&s);
        rowA[r][c0 + j] = __bfloat162float(hb);
      }
    } else {
      const float* ap = (const float*)A + (size_t)rr * EMBED + c0;
#pragma unroll
      for (int j = 0; j < 8; ++j) rowA[r][c0 + j] = ap[j];
    }
  }
  __syncthreads();

  const int n = t;                        // column, N = 256 fixed
  const float b = ldf<BF>(bias, n);
  float acc[8];
#pragma unroll
  for (int r = 0; r < 8; ++r) acc[r] = b;
#pragma unroll 4
  for (int k = 0; k < EMBED; ++k) {
    float w = ldf<BF>(W, (size_t)k * EMBED + n);
#pragma unroll
    for (int r = 0; r < 8; ++r) acc[r] = fmaf(rowA[r][k], w, acc[r]);
  }
#pragma unroll
  for (int r = 0; r < 8; ++r)
    if (r0 + r < M) C[(size_t)(r0 + r) * EMBED + n] = acc[r];
}

__global__ __launch_bounds__(256)
void k_vgemv8(const void* A, const void* W, const void* bias, float* C,
              int M, const int* flag) {
  if (*flag) vgemv8_body<true >(A, W, bias, C, M);
  else       vgemv8_body<false>(A, W, bias, C, M);
}

// ---------------------------------------------------------------------------
// R8 k_fused: attn GEMV (256-thread K-split) + softmax + pack + gather.
// ---------------------------------------------------------------------------
template<bool BF, class VT>
__device__ void fused_body(const void* __restrict__ query,
                           const void* __restrict__ ref_points,
                           const float* __restrict__ off_pre,
                           const void* __restrict__ W_attn,
                           const void* __restrict__ b_attn,
                           const VT* __restrict__ v,
                           void* __restrict__ out, int N, int BN) {
  int q = blockIdx.x;
  if (q >= BN) return;
  int b = q / N;
  int t = threadIdx.x;

  __shared__ float  row[EMBED];
  __shared__ float  s_part[256];
  __shared__ float  s_aw[HEADS * LEVELS * POINTS];
  __shared__ float  s_rp[2];
  __shared__ int4   s_pi[HEADS * LEVELS * POINTS];   // cell index * EMBED
  __shared__ float4 s_pw[HEADS * LEVELS * POINTS];   // wa*bilinear*valid

  row[t] = ldf<BF>(query, (size_t)q * EMBED + t);
  if (t < 2) s_rp[t] = ldf<BF>(ref_points, (size_t)q * 2 + t);
  __syncthreads();

  // attn GEMV: all 256 threads; col = t&127, K-half = t>>7
  {
    const int col = t & 127;
    const int e0  = (t >> 7) * 128;
    float acc = 0.f;
#pragma unroll 8
    for (int e = 0; e < 128; ++e)
      acc = fmaf(row[e0 + e], ldf<BF>(W_attn, (size_t)(e0 + e) * 128 + col), acc);
    s_part[t] = acc;
  }
  __syncthreads();
  if (t < 128)
    s_aw[t] = ldf<BF>(b_attn, t) + s_part[t] + s_part[t + 128];
  __syncthreads();

  if (t < 128) {
    // softmax over this head's 16 scores; thread t owns combo t = (h,l,p)
    int base = t & ~15;
    float mx = -1e30f;
#pragma unroll
    for (int i = 0; i < 16; ++i) mx = fmaxf(mx, s_aw[base + i]);
    float sum = 0.f;
#pragma unroll
    for (int i = 0; i < 16; ++i) sum += expf(s_aw[base + i] - mx);
    float wa = expf(s_aw[t] - mx) / sum;

    // pack: combo t -> l = (t>>2)&3, p = t&3 (h implicit in t)
    int   l  = (t >> 2) & 3;
    int   Wl = 128 >> l;                       // levels are square
    float fW = (float)Wl;
    int   st = (int)((65536u - (65536u >> (2 * l))) / 3u);  // level start
    // (rp + off/fW)*fW - 0.5 == rp*fW + off - 0.5  (fW power of two, exact)
    float ox = off_pre[(size_t)q * EMBED + 2 * t]     - 0.5f;
    float oy = off_pre[(size_t)q * EMBED + 2 * t + 1] - 0.5f;
    float x = fmaf(s_rp[0], fW, ox);
    float y = fmaf(s_rp[1], fW, oy);
    float x0f = floorf(x), y0f = floorf(y);
    float lx = x - x0f, ly = y - y0f;
    int x0 = (int)x0f, y0 = (int)y0f;
    int x1 = x0 + 1,   y1 = y0 + 1;
    float w00 = wa * (1.f - lx) * (1.f - ly);
    float w01 = wa * lx * (1.f - ly);
    float w10 = wa * (1.f - lx) * ly;
    float w11 = wa * lx * ly;
    bool vx0 = (unsigned)x0 < (unsigned)Wl;
    bool vx1 = (unsigned)x1 < (unsigned)Wl;
    bool vy0 = (unsigned)y0 < (unsigned)Wl;
    bool vy1 = (unsigned)y1 < (unsigned)Wl;
    int xc0 = min(max(x0, 0), Wl - 1), xc1 = min(max(x1, 0), Wl - 1);
    int yc0 = min(max(y0, 0), Wl - 1), yc1 = min(max(y1, 0), Wl - 1);
    int r0i = st + yc0 * Wl;
    int r1i = st + yc1 * Wl;
    int4 pi; float4 pw;
    pi.x = (r0i + xc0) << 8;  pw.x = (vx0 && vy0) ? w00 : 0.f;
    pi.y = (r0i + xc1) << 8;  pw.y = (vx1 && vy0) ? w01 : 0.f;
    pi.z = (r1i + xc0) << 8;  pw.z = (vx0 && vy1) ? w10 : 0.f;
    pi.w = (r1i + xc1) << 8;  pw.w = (vx1 && vy1) ? w11 : 0.f;
    s_pi[t] = pi;
    s_pw[t] = pw;
  }
  __syncthreads();

  // gather: per thread 16 combos x 4 corners; LDS reads broadcast per head
  const int h = t >> 5;
  const VT* vbt = v + (size_t)b * M_TOT * EMBED + t;
  float o = 0.f;
#pragma unroll
  for (int lp = 0; lp < 16; ++lp) {
    int c = (h << 4) + lp;
    int4   i4 = s_pi[c];
    float4 w4 = s_pw[c];
    o = fmaf(w4.x, vt2f(vbt[i4.x]), o);
    o = fmaf(w4.y, vt2f(vbt[i4.y]), o);
    o = fmaf(w4.z, vt2f(vbt[i4.z]), o);
    o = fmaf(w4.w, vt2f(vbt[i4.w]), o);
  }
  if (BF) ((bf16*)out)[(size_t)q * EMBED + t] = __float2bfloat16(o);
  else    ((float*)out)[(size_t)q * EMBED + t] = o;
}

template<class VT>
__global__ __launch_bounds__(256)
void k_fused(const void* query, const void* ref_points, const float* off_pre,
             const void* W_attn, const void* b_attn,
             const VT* v, void* out, int N, int BN, const int* flag) {
  if (*flag) fused_body<true,  VT>(query, ref_points, off_pre, W_attn, b_attn, v, out, N, BN);
  else       fused_body<false, VT>(query, ref_points, off_pre, W_attn, b_attn, v, out, N, BN);
}

// ---------------------------------------------------------------------------
// Fallback path (ws too small): R2/R6's bf16 fused path, fully self-contained.
// ---------------------------------------------------------------------------
template<bool BF, class VT>
__device__ void vproj_body(const void* __restrict__ value,
                           const void* __restrict__ W_v,
                           const void* __restrict__ b_v,
                           VT* __restrict__ v, int BM) {
  int m = blockIdx.x;
  if (m >= BM) return;
  int t = threadIdx.x;
  __shared__ float row[EMBED];
  row[t] = ldf<BF>(value, (size_t)m * EMBED + t);
  __syncthreads();
  float acc = ldf<BF>(b_v, t);
#pragma unroll 8
  for (int e = 0; e < EMBED; ++e)
    acc = fmaf(row[e], ldf<BF>(W_v, (size_t)e * EMBED + t), acc);
  if (sizeof(VT) == 2) ((bf16*)v)[(size_t)m * EMBED + t] = __float2bfloat16(acc);
  else                 ((float*)v)[(size_t)m * EMBED + t] = acc;
}

template<class VT>
__global__ __launch_bounds__(256)
void k_value_proj(const void* value, const void* W_v, const void* b_v,
                  VT* v, int BM, const int* flag) {
  if (*flag) vproj_body<true,  VT>(value, W_v, b_v, v, BM);
  else       vproj_body<false, VT>(value, W_v, b_v, v, BM);
}

template<bool BF, class VT>
__device__ void fusedfb_body(const void* __restrict__ query,
                             const void* __restrict__ ref_points,
                             const void* __restrict__ W_off,
                             const void* __restrict__ b_off,
                             const void* __restrict__ W_attn,
                             const void* __restrict__ b_attn,
                             const VT* __restrict__ v,
                             void* __restrict__ out, int N, int BN) {
  int q = blockIdx.x;
  if (q >= BN) return;
  int b = q / N;
  int t = threadIdx.x;

  __shared__ float row[EMBED];
  __shared__ float s_off[EMBED];
  __shared__ float s_aw[HEADS * LEVELS * POINTS];
  __shared__ float s_rp[2];

  row[t] = ldf<BF>(query, (size_t)q * EMBED + t);
  if (t < 2) s_rp[t] = ldf<BF>(ref_points, (size_t)q * 2 + t);
  __syncthreads();

  {
    float acc = ldf<BF>(b_off, t);
#pragma unroll 8
    for (int e = 0; e < EMBED; ++e)
      acc = fmaf(row[e], ldf<BF>(W_off, (size_t)e * EMBED + t), acc);
    s_off[t] = acc;
  }
  if (t < 128) {
    float acc = ldf<BF>(b_attn, t);
#pragma unroll 8
    for (int e = 0; e < EMBED; ++e)
      acc = fmaf(row[e], ldf<BF>(W_attn, (size_t)e * 128 + t), acc);
    s_aw[t] = acc;
  }
  __syncthreads();

  float aval = 0.f;
  if (t < 128) {
    int base = t & ~15;
    float mx = -1e30f;
#pragma unroll
    for (int i = 0; i < 16; ++i) mx = fmaxf(mx, s_aw[base + i]);
    float sum = 0.f;
#pragma unroll
    for (int i = 0; i < 16; ++i) sum += expf(s_aw[base + i] - mx);
    aval = expf(s_aw[t] - mx) / sum;
  }
  __syncthreads();
  if (t < 128) s_aw[t] = aval;
  __syncthreads();

  int h = t >> 5;
  const VT* vb = v + (size_t)b * M_TOT * EMBED;
  float o = 0.f;
#pragma unroll
  for (int l = 0; l < LEVELS; ++l) {
    const int Hl = c_H[l], Wl = c_H[l];
    const VT* vl = vb + (size_t)c_St[l] * EMBED;
    const float fW = (float)Wl, fH = (float)Hl;
#pragma unroll
    for (int p = 0; p < POINTS; ++p) {
      int oi = ((h * LEVELS + l) * POINTS + p) << 1;
      float x = (s_rp[0] + s_off[oi]     / fW) * fW - 0.5f;
      float y = (s_rp[1] + s_off[oi + 1] / fH) * fH - 0.5f;
      float x0f = floorf(x), y0f = floorf(y);
      float lx = x - x0f, ly = y - y0f;
      int x0 = (int)x0f, y0 = (int)y0f;
      float wa = s_aw[(h * LEVELS + l) * POINTS + p];
      float cw[4] = {(1.f - lx) * (1.f - ly), lx * (1.f - ly),
                     (1.f - lx) * ly,         lx * ly};
      const int dxs[4] = {0, 1, 0, 1};
      const int dys[4] = {0, 0, 1, 1};
#pragma unroll
      for (int cidx = 0; cidx < 4; ++cidx) {
        int xi = x0 + dxs[cidx];
        int yi = y0 + dys[cidx];
        bool valid = (xi >= 0) & (xi < Wl) & (yi >= 0) & (yi < Hl);
        int xc = min(max(xi, 0), Wl - 1);
        int yc = min(max(yi, 0), Hl - 1);
        float g = vt2f(vl[(size_t)(yc * Wl + xc) * EMBED + t]);
        o += (valid ? wa * cw[cidx] : 0.f) * g;
      }
    }
  }
  if (BF) ((bf16*)out)[(size_t)q * EMBED + t] = __float2bfloat16(o);
  else    ((float*)out)[(size_t)q * EMBED + t] = o;
}

template<class VT>
__global__ __launch_bounds__(256)
void k_fused_fb(const void* query, const void* ref_points,
                const void* W_off, const void* b_off,
                const void* W_attn, const void* b_attn,
                const VT* v, void* out, int N, int BN, const int* flag) {
  if (*flag) fusedfb_body<true,  VT>(query, ref_points, W_off, b_off, W_attn, b_attn, v, out, N, BN);
  else       fusedfb_body<false, VT>(query, ref_points, W_off, b_off, W_attn, b_attn, v, out, N, BN);
}

// ---------------------------------------------------------------------------
extern "C" void kernel_launch(void* const* d_in, const int* in_sizes, int n_in,
                              void* d_out, int out_size, void* d_ws, size_t ws_size,
                              hipStream_t stream) {
  const void* query      = d_in[0];
  const void* value      = d_in[2];
  const void* ref_points = d_in[3];
  const void* W_off  = d_in[6];
  const void* b_off  = d_in[7];
  const void* W_attn = d_in[8];
  const void* b_attn = d_in[9];
  const void* W_v    = d_in[10];
  const void* b_v    = d_in[11];

  const int BN = in_sizes[0] / EMBED;   // 20000
  const int BM = in_sizes[2] / EMBED;   // 43520
  const int N  = BN / BATCH;

  int*  flag    = (int*)d_ws;
  char* ws_base = (char*)d_ws + 256;

  k_detect<<<1, 256, 0, stream>>>((const unsigned short*)query, flag);

  const size_t need = 256 + (size_t)BM * EMBED * sizeof(float)
                          + (size_t)BN * EMBED * sizeof(float);
  if (ws_size >= need) {
    float* ws_v   = (float*)ws_base;
    float* ws_off = ws_v + (size_t)BM * EMBED;
    k_vgemv8<<<(BM + 7) / 8, 256, 0, stream>>>(value, W_v, b_v, ws_v, BM, flag);
    k_vgemv8<<<(BN + 7) / 8, 256, 0, stream>>>(query, W_off, b_off, ws_off, BN, flag);
    k_fused<float><<<BN, 256, 0, stream>>>(query, ref_points, ws_off,
                                           W_attn, b_attn, ws_v, d_out, N, BN, flag);
  } else {
    bf16* ws_v = (bf16*)ws_base;
    k_value_proj<bf16><<<BM, 256, 0, stream>>>(value, W_v, b_v, ws_v, BM, flag);
    k_fused_fb<bf16><<<BN, 256, 0, stream>>>(query, ref_points, W_off, b_off,
                                             W_attn, b_attn, ws_v, d_out, N, BN, flag);
  }
}

// Round 2
// 497.233 us; speedup vs baseline: 1.1216x; 1.1216x over previous
//
#include <hip/hip_runtime.h>
#include <hip/hip_bf16.h>

// DeformableAttention3D — MI355X (gfx950)
// R9: k_fused was LATENCY-bound (R8: VALUBusy 93->38%, dur unchanged).
//   * attn GEMV hoisted out of k_fused into k_agemv16 (16 rows/block,
//     W_attn traffic 2.56GB -> 160MB; removes 128 L2 loads/thread from hot kernel)
//   * gather restructured: 16 loads batched in flight per group, 2 accumulators
//   * 16-row GEMVs for value/off projections (halve W re-read vs 8-row)
// Tiers: full (v+off+scores in ws) -> R8 mid path -> R2/R6 bf16 fallback.
#define EMBED    256
#define HEADS    8
#define LEVELS   4
#define POINTS   4
#define BATCH    2
#define M_TOT    21760   // 128*128 + 64*64 + 32*32 + 16*16

typedef __hip_bfloat16 bf16;
typedef __attribute__((ext_vector_type(8))) short short8;

__device__ __constant__ int c_H[LEVELS]  = {128, 64, 32, 16};
__device__ __constant__ int c_St[LEVELS] = {0, 16384, 20480, 21504};

template<bool BF>
__device__ __forceinline__ float ldf(const void* p, size_t i) {
  if (BF) return __bfloat162float(((const bf16*)p)[i]);
  else    return ((const float*)p)[i];
}
__device__ __forceinline__ float vt2f(float x) { return x; }
__device__ __forceinline__ float vt2f(bf16 x)  { return __bfloat162float(x); }

// ---------------------------------------------------------------------------
// Dtype detector (flag=1 -> buffers bf16, flag=0 -> f32). Verbatim.
// ---------------------------------------------------------------------------
__global__ __launch_bounds__(256)
void k_detect(const unsigned short* __restrict__ q16, int* __restrict__ flag) {
  __shared__ int cnt;
  if (threadIdx.x == 0) cnt = 0;
  __syncthreads();
  int c = 0;
  for (int i = threadIdx.x; i < 8192; i += 256) {
    unsigned short v = q16[i];
    if ((v & 0x7F80u) == 0x7F80u) ++c;   // bf16 Inf/NaN pattern
  }
  if (c) atomicAdd(&cnt, c);
  __syncthreads();
  if (threadIdx.x == 0) flag[0] = (cnt == 0) ? 1 : 0;
}

// ---------------------------------------------------------------------------
// R9: 16-rows-per-block GEMV, N = 256. C[M x 256] = A[M x 256] @ W + bias.
// ---------------------------------------------------------------------------
template<bool BF>
__device__ void vgemv16_body(const void* __restrict__ A, const void* __restrict__ W,
                             const void* __restrict__ bias, float* __restrict__ C,
                             int M) {
  const int t  = threadIdx.x;            // 256 threads
  const int r0 = blockIdx.x * 16;
  if (r0 >= M) return;

  __shared__ float rowA[16][EMBED];
  {
    int r  = t >> 4;                     // 0..15
    int rr = min(r0 + r, M - 1);         // clamp reads; stores guarded
    int c0 = (t & 15) * 16;              // 0..240
    if (BF) {
      const bf16* ap = (const bf16*)A + (size_t)rr * EMBED + c0;
      short8 a0 = *(const short8*)ap;
      short8 a1 = *(const short8*)(ap + 8);
#pragma unroll
      for (int j = 0; j < 8; ++j) {
        short s0 = a0[j], s1 = a1[j];
        rowA[r][c0 + j]     = __bfloat162float(*reinterpret_cast<bf16*>(&s0));
        rowA[r][c0 + 8 + j] = __bfloat162float(*reinterpret_cast<bf16*>(&s1));
      }
    } else {
      const float* ap = (const float*)A + (size_t)rr * EMBED + c0;
#pragma unroll
      for (int j = 0; j < 4; ++j) {
        float4 f = *(const float4*)(ap + j * 4);
        rowA[r][c0 + j * 4 + 0] = f.x;
        rowA[r][c0 + j * 4 + 1] = f.y;
        rowA[r][c0 + j * 4 + 2] = f.z;
        rowA[r][c0 + j * 4 + 3] = f.w;
      }
    }
  }
  __syncthreads();

  const int n = t;                        // column
  const float b = ldf<BF>(bias, n);
  float acc[16];
#pragma unroll
  for (int r = 0; r < 16; ++r) acc[r] = b;
#pragma unroll 2
  for (int k = 0; k < EMBED; ++k) {
    float w = ldf<BF>(W, (size_t)k * EMBED + n);
#pragma unroll
    for (int r = 0; r < 16; ++r) acc[r] = fmaf(rowA[r][k], w, acc[r]);
  }
#pragma unroll
  for (int r = 0; r < 16; ++r)
    if (r0 + r < M) C[(size_t)(r0 + r) * EMBED + n] = acc[r];
}

__global__ __launch_bounds__(256)
void k_vgemv16(const void* A, const void* W, const void* bias, float* C,
               int M, const int* flag) {
  if (*flag) vgemv16_body<true >(A, W, bias, C, M);
  else       vgemv16_body<false>(A, W, bias, C, M);
}

// ---------------------------------------------------------------------------
// R9: attn-score GEMV. C[M x 128] = A[M x 256] @ W[256 x 128] + bias.
// 16 rows/block; 256 threads = (col 0..127) x (K-half 0..1); LDS combine.
// ---------------------------------------------------------------------------
template<bool BF>
__device__ void agemv16_body(const void* __restrict__ A, const void* __restrict__ W,
                             const void* __restrict__ bias, float* __restrict__ C,
                             int M) {
  const int t  = threadIdx.x;
  const int r0 = blockIdx.x * 16;
  if (r0 >= M) return;

  __shared__ float sh[16 * EMBED];       // rows; reused as comb[16][256]
  {
    int r  = t >> 4;
    int rr = min(r0 + r, M - 1);
    int c0 = (t & 15) * 16;
    if (BF) {
      const bf16* ap = (const bf16*)A + (size_t)rr * EMBED + c0;
      short8 a0 = *(const short8*)ap;
      short8 a1 = *(const short8*)(ap + 8);
#pragma unroll
      for (int j = 0; j < 8; ++j) {
        short s0 = a0[j], s1 = a1[j];
        sh[r * EMBED + c0 + j]     = __bfloat162float(*reinterpret_cast<bf16*>(&s0));
        sh[r * EMBED + c0 + 8 + j] = __bfloat162float(*reinterpret_cast<bf16*>(&s1));
      }
    } else {
      const float* ap = (const float*)A + (size_t)rr * EMBED + c0;
#pragma unroll
      for (int j = 0; j < 4; ++j) {
        float4 f = *(const float4*)(ap + j * 4);
        sh[r * EMBED + c0 + j * 4 + 0] = f.x;
        sh[r * EMBED + c0 + j * 4 + 1] = f.y;
        sh[r * EMBED + c0 + j * 4 + 2] = f.z;
        sh[r * EMBED + c0 + j * 4 + 3] = f.w;
      }
    }
  }
  __syncthreads();

  const int col = t & 127;
  const int e0  = (t >> 7) << 7;         // 0 or 128
  float acc[16];
#pragma unroll
  for (int r = 0; r < 16; ++r) acc[r] = 0.f;
#pragma unroll 2
  for (int k = 0; k < 128; ++k) {
    float w = ldf<BF>(W, (size_t)(e0 + k) * 128 + col);
#pragma unroll
    for (int r = 0; r < 16; ++r) acc[r] = fmaf(sh[r * EMBED + e0 + k], w, acc[r]);
  }
  __syncthreads();                        // done reading rows
  // comb[r][t] layout (stride-1 across threads -> conflict-free)
#pragma unroll
  for (int r = 0; r < 16; ++r) sh[r * EMBED + t] = acc[r];
  __syncthreads();
  if (t < 128) {
    float b = ldf<BF>(bias, t);
#pragma unroll
    for (int r = 0; r < 16; ++r)
      if (r0 + r < M)
        C[(size_t)(r0 + r) * 128 + t] = b + sh[r * EMBED + t] + sh[r * EMBED + t + 128];
  }
}

__global__ __launch_bounds__(256)
void k_agemv16(const void* A, const void* W, const void* bias, float* C,
               int M, const int* flag) {
  if (*flag) agemv16_body<true >(A, W, bias, C, M);
  else       agemv16_body<false>(A, W, bias, C, M);
}

// ---------------------------------------------------------------------------
// R9 k_fused2: softmax + pack (t<128) + ILP-batched gather. No GEMV inside.
// ---------------------------------------------------------------------------
template<bool BF>
__device__ void fused2_body(const void* __restrict__ ref_points,
                            const float* __restrict__ off_pre,
                            const float* __restrict__ scores,
                            const float* __restrict__ v,
                            void* __restrict__ out, int N, int BN) {
  int q = blockIdx.x;
  if (q >= BN) return;
  int b = q / N;
  int t = threadIdx.x;

  __shared__ float  s_aw[128];
  __shared__ float  s_rp[2];
  __shared__ int4   s_pi[128];   // corner element index (cell<<8)
  __shared__ float4 s_pw[128];   // wa * bilinear * valid

  if (t < 2)   s_rp[t] = ldf<BF>(ref_points, (size_t)q * 2 + t);
  if (t < 128) s_aw[t] = scores[(size_t)q * 128 + t];
  __syncthreads();

  if (t < 128) {
    // softmax over this head's 16 scores; thread t owns combo t = (h,l,p)
    int base = t & ~15;
    float mx = -1e30f;
#pragma unroll
    for (int i = 0; i < 16; ++i) mx = fmaxf(mx, s_aw[base + i]);
    float sum = 0.f;
#pragma unroll
    for (int i = 0; i < 16; ++i) sum += expf(s_aw[base + i] - mx);
    float wa = expf(s_aw[t] - mx) / sum;

    // pack (verbatim R8, proven): combo t -> l = (t>>2)&3, p = t&3
    int   l  = (t >> 2) & 3;
    int   Wl = 128 >> l;                       // levels are square
    float fW = (float)Wl;
    int   st = (int)((65536u - (65536u >> (2 * l))) / 3u);  // level start
    // (rp + off/fW)*fW - 0.5 == rp*fW + off - 0.5  (fW power of two, exact)
    float ox = off_pre[(size_t)q * EMBED + 2 * t]     - 0.5f;
    float oy = off_pre[(size_t)q * EMBED + 2 * t + 1] - 0.5f;
    float x = fmaf(s_rp[0], fW, ox);
    float y = fmaf(s_rp[1], fW, oy);
    float x0f = floorf(x), y0f = floorf(y);
    float lx = x - x0f, ly = y - y0f;
    int x0 = (int)x0f, y0 = (int)y0f;
    int x1 = x0 + 1,   y1 = y0 + 1;
    float w00 = wa * (1.f - lx) * (1.f - ly);
    float w01 = wa * lx * (1.f - ly);
    float w10 = wa * (1.f - lx) * ly;
    float w11 = wa * lx * ly;
    bool vx0 = (unsigned)x0 < (unsigned)Wl;
    bool vx1 = (unsigned)x1 < (unsigned)Wl;
    bool vy0 = (unsigned)y0 < (unsigned)Wl;
    bool vy1 = (unsigned)y1 < (unsigned)Wl;
    int xc0 = min(max(x0, 0), Wl - 1), xc1 = min(max(x1, 0), Wl - 1);
    int yc0 = min(max(y0, 0), Wl - 1), yc1 = min(max(y1, 0), Wl - 1);
    int r0i = st + yc0 * Wl;
    int r1i = st + yc1 * Wl;
    int4 pi; float4 pw;
    pi.x = (r0i + xc0) << 8;  pw.x = (vx0 && vy0) ? w00 : 0.f;
    pi.y = (r0i + xc1) << 8;  pw.y = (vx1 && vy0) ? w01 : 0.f;
    pi.z = (r1i + xc0) << 8;  pw.z = (vx0 && vy1) ? w10 : 0.f;
    pi.w = (r1i + xc1) << 8;  pw.w = (vx1 && vy1) ? w11 : 0.f;
    s_pi[t] = pi;
    s_pw[t] = pw;
  }
  __syncthreads();

  // gather: 16 combos x 4 corners for this head; 16 loads in flight per group
  const float* vb = v + (size_t)b * (M_TOT * EMBED);
  const int cb = (t >> 5) << 4;            // h*16
  float o0 = 0.f, o1 = 0.f;
#pragma unroll
  for (int g = 0; g < 4; ++g) {
    const int c0 = cb + (g << 2);
    int4   iA = s_pi[c0 + 0], iB = s_pi[c0 + 1], iC = s_pi[c0 + 2], iD = s_pi[c0 + 3];
    float4 wA = s_pw[c0 + 0], wB = s_pw[c0 + 1], wC = s_pw[c0 + 2], wD = s_pw[c0 + 3];
    float gA0 = vb[iA.x + t], gA1 = vb[iA.y + t], gA2 = vb[iA.z + t], gA3 = vb[iA.w + t];
    float gB0 = vb[iB.x + t], gB1 = vb[iB.y + t], gB2 = vb[iB.z + t], gB3 = vb[iB.w + t];
    float gC0 = vb[iC.x + t], gC1 = vb[iC.y + t], gC2 = vb[iC.z + t], gC3 = vb[iC.w + t];
    float gD0 = vb[iD.x + t], gD1 = vb[iD.y + t], gD2 = vb[iD.z + t], gD3 = vb[iD.w + t];
    o0 = fmaf(wA.x, gA0, o0); o1 = fmaf(wA.y, gA1, o1);
    o0 = fmaf(wA.z, gA2, o0); o1 = fmaf(wA.w, gA3, o1);
    o0 = fmaf(wB.x, gB0, o0); o1 = fmaf(wB.y, gB1, o1);
    o0 = fmaf(wB.z, gB2, o0); o1 = fmaf(wB.w, gB3, o1);
    o0 = fmaf(wC.x, gC0, o0); o1 = fmaf(wC.y, gC1, o1);
    o0 = fmaf(wC.z, gC2, o0); o1 = fmaf(wC.w, gC3, o1);
    o0 = fmaf(wD.x, gD0, o0); o1 = fmaf(wD.y, gD1, o1);
    o0 = fmaf(wD.z, gD2, o0); o1 = fmaf(wD.w, gD3, o1);
  }
  float o = o0 + o1;
  if (BF) ((bf16*)out)[(size_t)q * EMBED + t] = __float2bfloat16(o);
  else    ((float*)out)[(size_t)q * EMBED + t] = o;
}

__global__ __launch_bounds__(256)
void k_fused2(const void* ref_points, const float* off_pre, const float* scores,
              const float* v, void* out, int N, int BN, const int* flag) {
  if (*flag) fused2_body<true >(ref_points, off_pre, scores, v, out, N, BN);
  else       fused2_body<false>(ref_points, off_pre, scores, v, out, N, BN);
}

// ---------------------------------------------------------------------------
// MID TIER (R8, proven): 8-row GEMV + fused with in-kernel attn GEMV.
// ---------------------------------------------------------------------------
template<bool BF>
__device__ void vgemv8_body(const void* __restrict__ A, const void* __restrict__ W,
                            const void* __restrict__ bias, float* __restrict__ C,
                            int M) {
  const int t  = threadIdx.x;
  const int r0 = blockIdx.x * 8;
  if (r0 >= M) return;

  __shared__ float rowA[8][EMBED];
  {
    int r  = t >> 5;
    int rr = min(r0 + r, M - 1);
    int c0 = (t & 31) * 8;
    if (BF) {
      const bf16* ap = (const bf16*)A + (size_t)rr * EMBED + c0;
      short8 a = *(const short8*)ap;
#pragma unroll
      for (int j = 0; j < 8; ++j) {
        short s = a[j];
        bf16 hb = *reinterpret_cast<bf16*>(&s);
        rowA[r][c0 + j] = __bfloat162float(hb);
      }
    } else {
      const float* ap = (const float*)A + (size_t)rr * EMBED + c0;
#pragma unroll
      for (int j = 0; j < 8; ++j) rowA[r][c0 + j] = ap[j];
    }
  }
  __syncthreads();

  const int n = t;
  const float b = ldf<BF>(bias, n);
  float acc[8];
#pragma unroll
  for (int r = 0; r < 8; ++r) acc[r] = b;
#pragma unroll 4
  for (int k = 0; k < EMBED; ++k) {
    float w = ldf<BF>(W, (size_t)k * EMBED + n);
#pragma unroll
    for (int r = 0; r < 8; ++r) acc[r] = fmaf(rowA[r][k], w, acc[r]);
  }
#pragma unroll
  for (int r = 0; r < 8; ++r)
    if (r0 + r < M) C[(size_t)(r0 + r) * EMBED + n] = acc[r];
}

__global__ __launch_bounds__(256)
void k_vgemv8(const void* A, const void* W, const void* bias, float* C,
              int M, const int* flag) {
  if (*flag) vgemv8_body<true >(A, W, bias, C, M);
  else       vgemv8_body<false>(A, W, bias, C, M);
}

template<bool BF, class VT>
__device__ void fused_body(const void* __restrict__ query,
                           const void* __restrict__ ref_points,
                           const float* __restrict__ off_pre,
                           const void* __restrict__ W_attn,
                           const void* __restrict__ b_attn,
                           const VT* __restrict__ v,
                           void* __restrict__ out, int N, int BN) {
  int q = blockIdx.x;
  if (q >= BN) return;
  int b = q / N;
  int t = threadIdx.x;

  __shared__ float  row[EMBED];
  __shared__ float  s_part[256];
  __shared__ float  s_aw[HEADS * LEVELS * POINTS];
  __shared__ float  s_rp[2];
  __shared__ int4   s_pi[HEADS * LEVELS * POINTS];
  __shared__ float4 s_pw[HEADS * LEVELS * POINTS];

  row[t] = ldf<BF>(query, (size_t)q * EMBED + t);
  if (t < 2) s_rp[t] = ldf<BF>(ref_points, (size_t)q * 2 + t);
  __syncthreads();

  {
    const int col = t & 127;
    const int e0  = (t >> 7) * 128;
    float acc = 0.f;
#pragma unroll 8
    for (int e = 0; e < 128; ++e)
      acc = fmaf(row[e0 + e], ldf<BF>(W_attn, (size_t)(e0 + e) * 128 + col), acc);
    s_part[t] = acc;
  }
  __syncthreads();
  if (t < 128)
    s_aw[t] = ldf<BF>(b_attn, t) + s_part[t] + s_part[t + 128];
  __syncthreads();

  if (t < 128) {
    int base = t & ~15;
    float mx = -1e30f;
#pragma unroll
    for (int i = 0; i < 16; ++i) mx = fmaxf(mx, s_aw[base + i]);
    float sum = 0.f;
#pragma unroll
    for (int i = 0; i < 16; ++i) sum += expf(s_aw[base + i] - mx);
    float wa = expf(s_aw[t] - mx) / sum;

    int   l  = (t >> 2) & 3;
    int   Wl = 128 >> l;
    float fW = (float)Wl;
    int   st = (int)((65536u - (65536u >> (2 * l))) / 3u);
    float ox = off_pre[(size_t)q * EMBED + 2 * t]     - 0.5f;
    float oy = off_pre[(size_t)q * EMBED + 2 * t + 1] - 0.5f;
    float x = fmaf(s_rp[0], fW, ox);
    float y = fmaf(s_rp[1], fW, oy);
    float x0f = floorf(x), y0f = floorf(y);
    float lx = x - x0f, ly = y - y0f;
    int x0 = (int)x0f, y0 = (int)y0f;
    int x1 = x0 + 1,   y1 = y0 + 1;
    float w00 = wa * (1.f - lx) * (1.f - ly);
    float w01 = wa * lx * (1.f - ly);
    float w10 = wa * (1.f - lx) * ly;
    float w11 = wa * lx * ly;
    bool vx0 = (unsigned)x0 < (unsigned)Wl;
    bool vx1 = (unsigned)x1 < (unsigned)Wl;
    bool vy0 = (unsigned)y0 < (unsigned)Wl;
    bool vy1 = (unsigned)y1 < (unsigned)Wl;
    int xc0 = min(max(x0, 0), Wl - 1), xc1 = min(max(x1, 0), Wl - 1);
    int yc0 = min(max(y0, 0), Wl - 1), yc1 = min(max(y1, 0), Wl - 1);
    int r0i = st + yc0 * Wl;
    int r1i = st + yc1 * Wl;
    int4 pi; float4 pw;
    pi.x = (r0i + xc0) << 8;  pw.x = (vx0 && vy0) ? w00 : 0.f;
    pi.y = (r0i + xc1) << 8;  pw.y = (vx1 && vy0) ? w01 : 0.f;
    pi.z = (r1i + xc0) << 8;  pw.z = (vx0 && vy1) ? w10 : 0.f;
    pi.w = (r1i + xc1) << 8;  pw.w = (vx1 && vy1) ? w11 : 0.f;
    s_pi[t] = pi;
    s_pw[t] = pw;
  }
  __syncthreads();

  const int h = t >> 5;
  const VT* vbt = v + (size_t)b * M_TOT * EMBED + t;
  float o = 0.f;
#pragma unroll
  for (int lp = 0; lp < 16; ++lp) {
    int c = (h << 4) + lp;
    int4   i4 = s_pi[c];
    float4 w4 = s_pw[c];
    o = fmaf(w4.x, vt2f(vbt[i4.x]), o);
    o = fmaf(w4.y, vt2f(vbt[i4.y]), o);
    o = fmaf(w4.z, vt2f(vbt[i4.z]), o);
    o = fmaf(w4.w, vt2f(vbt[i4.w]), o);
  }
  if (BF) ((bf16*)out)[(size_t)q * EMBED + t] = __float2bfloat16(o);
  else    ((float*)out)[(size_t)q * EMBED + t] = o;
}

template<class VT>
__global__ __launch_bounds__(256)
void k_fused(const void* query, const void* ref_points, const float* off_pre,
             const void* W_attn, const void* b_attn,
             const VT* v, void* out, int N, int BN, const int* flag) {
  if (*flag) fused_body<true,  VT>(query, ref_points, off_pre, W_attn, b_attn, v, out, N, BN);
  else       fused_body<false, VT>(query, ref_points, off_pre, W_attn, b_attn, v, out, N, BN);
}

// ---------------------------------------------------------------------------
// Fallback path (ws too small): R2/R6's bf16 fused path, fully self-contained.
// ---------------------------------------------------------------------------
template<bool BF, class VT>
__device__ void vproj_body(const void* __restrict__ value,
                           const void* __restrict__ W_v,
                           const void* __restrict__ b_v,
                           VT* __restrict__ v, int BM) {
  int m = blockIdx.x;
  if (m >= BM) return;
  int t = threadIdx.x;
  __shared__ float row[EMBED];
  row[t] = ldf<BF>(value, (size_t)m * EMBED + t);
  __syncthreads();
  float acc = ldf<BF>(b_v, t);
#pragma unroll 8
  for (int e = 0; e < EMBED; ++e)
    acc = fmaf(row[e], ldf<BF>(W_v, (size_t)e * EMBED + t), acc);
  if (sizeof(VT) == 2) ((bf16*)v)[(size_t)m * EMBED + t] = __float2bfloat16(acc);
  else                 ((float*)v)[(size_t)m * EMBED + t] = acc;
}

template<class VT>
__global__ __launch_bounds__(256)
void k_value_proj(const void* value, const void* W_v, const void* b_v,
                  VT* v, int BM, const int* flag) {
  if (*flag) vproj_body<true,  VT>(value, W_v, b_v, v, BM);
  else       vproj_body<false, VT>(value, W_v, b_v, v, BM);
}

template<bool BF, class VT>
__device__ void fusedfb_body(const void* __restrict__ query,
                             const void* __restrict__ ref_points,
                             const void* __restrict__ W_off,
                             const void* __restrict__ b_off,
                             const void* __restrict__ W_attn,
                             const void* __restrict__ b_attn,
                             const VT* __restrict__ v,
                             void* __restrict__ out, int N, int BN) {
  int q = blockIdx.x;
  if (q >= BN) return;
  int b = q / N;
  int t = threadIdx.x;

  __shared__ float row[EMBED];
  __shared__ float s_off[EMBED];
  __shared__ float s_aw[HEADS * LEVELS * POINTS];
  __shared__ float s_rp[2];

  row[t] = ldf<BF>(query, (size_t)q * EMBED + t);
  if (t < 2) s_rp[t] = ldf<BF>(ref_points, (size_t)q * 2 + t);
  __syncthreads();

  {
    float acc = ldf<BF>(b_off, t);
#pragma unroll 8
    for (int e = 0; e < EMBED; ++e)
      acc = fmaf(row[e], ldf<BF>(W_off, (size_t)e * EMBED + t), acc);
    s_off[t] = acc;
  }
  if (t < 128) {
    float acc = ldf<BF>(b_attn, t);
#pragma unroll 8
    for (int e = 0; e < EMBED; ++e)
      acc = fmaf(row[e], ldf<BF>(W_attn, (size_t)e * 128 + t), acc);
    s_aw[t] = acc;
  }
  __syncthreads();

  float aval = 0.f;
  if (t < 128) {
    int base = t & ~15;
    float mx = -1e30f;
#pragma unroll
    for (int i = 0; i < 16; ++i) mx = fmaxf(mx, s_aw[base + i]);
    float sum = 0.f;
#pragma unroll
    for (int i = 0; i < 16; ++i) sum += expf(s_aw[base + i] - mx);
    aval = expf(s_aw[t] - mx) / sum;
  }
  __syncthreads();
  if (t < 128) s_aw[t] = aval;
  __syncthreads();

  int h = t >> 5;
  const VT* vb = v + (size_t)b * M_TOT * EMBED;
  float o = 0.f;
#pragma unroll
  for (int l = 0; l < LEVELS; ++l) {
    const int Hl = c_H[l], Wl = c_H[l];
    const VT* vl = vb + (size_t)c_St[l] * EMBED;
    const float fW = (float)Wl, fH = (float)Hl;
#pragma unroll
    for (int p = 0; p < POINTS; ++p) {
      int oi = ((h * LEVELS + l) * POINTS + p) << 1;
      float x = (s_rp[0] + s_off[oi]     / fW) * fW - 0.5f;
      float y = (s_rp[1] + s_off[oi + 1] / fH) * fH - 0.5f;
      float x0f = floorf(x), y0f = floorf(y);
      float lx = x - x0f, ly = y - y0f;
      int x0 = (int)x0f, y0 = (int)y0f;
      float wa = s_aw[(h * LEVELS + l) * POINTS + p];
      float cw[4] = {(1.f - lx) * (1.f - ly), lx * (1.f - ly),
                     (1.f - lx) * ly,         lx * ly};
      const int dxs[4] = {0, 1, 0, 1};
      const int dys[4] = {0, 0, 1, 1};
#pragma unroll
      for (int cidx = 0; cidx < 4; ++cidx) {
        int xi = x0 + dxs[cidx];
        int yi = y0 + dys[cidx];
        bool valid = (xi >= 0) & (xi < Wl) & (yi >= 0) & (yi < Hl);
        int xc = min(max(xi, 0), Wl - 1);
        int yc = min(max(yi, 0), Hl - 1);
        float g = vt2f(vl[(size_t)(yc * Wl + xc) * EMBED + t]);
        o += (valid ? wa * cw[cidx] : 0.f) * g;
      }
    }
  }
  if (BF) ((bf16*)out)[(size_t)q * EMBED + t] = __float2bfloat16(o);
  else    ((float*)out)[(size_t)q * EMBED + t] = o;
}

template<class VT>
__global__ __launch_bounds__(256)
void k_fused_fb(const void* query, const void* ref_points,
                const void* W_off, const void* b_off,
                const void* W_attn, const void* b_attn,
                const VT* v, void* out, int N, int BN, const int* flag) {
  if (*flag) fusedfb_body<true,  VT>(query, ref_points, W_off, b_off, W_attn, b_attn, v, out, N, BN);
  else       fusedfb_body<false, VT>(query, ref_points, W_off, b_off, W_attn, b_attn, v, out, N, BN);
}

// ---------------------------------------------------------------------------
extern "C" void kernel_launch(void* const* d_in, const int* in_sizes, int n_in,
                              void* d_out, int out_size, void* d_ws, size_t ws_size,
                              hipStream_t stream) {
  const void* query      = d_in[0];
  const void* value      = d_in[2];
  const void* ref_points = d_in[3];
  const void* W_off  = d_in[6];
  const void* b_off  = d_in[7];
  const void* W_attn = d_in[8];
  const void* b_attn = d_in[9];
  const void* W_v    = d_in[10];
  const void* b_v    = d_in[11];

  const int BN = in_sizes[0] / EMBED;   // 20000
  const int BM = in_sizes[2] / EMBED;   // 43520
  const int N  = BN / BATCH;

  int*  flag    = (int*)d_ws;
  char* ws_base = (char*)d_ws + 256;

  k_detect<<<1, 256, 0, stream>>>((const unsigned short*)query, flag);

  const size_t sz_v    = (size_t)BM * EMBED * sizeof(float);
  const size_t sz_off  = (size_t)BN * EMBED * sizeof(float);
  const size_t sz_attn = (size_t)BN * 128 * sizeof(float);
  const size_t need_full = 256 + sz_v + sz_off + sz_attn;
  const size_t need_mid  = 256 + sz_v + sz_off;

  if (ws_size >= need_full) {
    float* ws_v    = (float*)ws_base;
    float* ws_off  = (float*)(ws_base + sz_v);
    float* ws_attn = (float*)(ws_base + sz_v + sz_off);
    k_vgemv16<<<(BM + 15) / 16, 256, 0, stream>>>(value, W_v, b_v, ws_v, BM, flag);
    k_vgemv16<<<(BN + 15) / 16, 256, 0, stream>>>(query, W_off, b_off, ws_off, BN, flag);
    k_agemv16<<<(BN + 15) / 16, 256, 0, stream>>>(query, W_attn, b_attn, ws_attn, BN, flag);
    k_fused2<<<BN, 256, 0, stream>>>(ref_points, ws_off, ws_attn, ws_v,
                                     d_out, N, BN, flag);
  } else if (ws_size >= need_mid) {
    float* ws_v   = (float*)ws_base;
    float* ws_off = (float*)(ws_base + sz_v);
    k_vgemv8<<<(BM + 7) / 8, 256, 0, stream>>>(value, W_v, b_v, ws_v, BM, flag);
    k_vgemv8<<<(BN + 7) / 8, 256, 0, stream>>>(query, W_off, b_off, ws_off, BN, flag);
    k_fused<float><<<BN, 256, 0, stream>>>(query, ref_points, ws_off,
                                           W_attn, b_attn, ws_v, d_out, N, BN, flag);
  } else {
    bf16* ws_v = (bf16*)ws_base;
    k_value_proj<bf16><<<BM, 256, 0, stream>>>(value, W_v, b_v, ws_v, BM, flag);
    k_fused_fb<bf16><<<BN, 256, 0, stream>>>(query, ref_points, W_off, b_off,
                                             W_attn, b_attn, ws_v, d_out, N, BN, flag);
  }
}

// Round 4
// 406.463 us; speedup vs baseline: 1.3721x; 1.2233x over previous
//
#include <hip/hip_runtime.h>
#include <hip/hip_bf16.h>

// DeformableAttention3D — MI355X (gfx950)
// R11 = R10 with the FMA4 macro replaced by an inline function (the macro
// parameter `w` captured the `.w` member access -> compile failure).
// Design unchanged:
//   * k_vgemv4x4: 4-row x 4-col register blocking. Per 4-k step:
//     4x ds_read_b128 (wave-uniform broadcast) + 4x global dwordx4 (W, coalesced)
//     + 64 FMA  ->  4 FMA per LDS dword (was 1 per b32). LDS traffic /4.
//   * k_agemv4: same structure for scores (N=128, 2-row x 4-col).
//   * k_fused2 / tiers verbatim from R9.
#define EMBED    256
#define HEADS    8
#define LEVELS   4
#define POINTS   4
#define BATCH    2
#define M_TOT    21760   // 128*128 + 64*64 + 32*32 + 16*16
#define LDP      (EMBED + 4)   // padded LDS leading dim (16B-aligned rows)

typedef __hip_bfloat16 bf16;
typedef __attribute__((ext_vector_type(8))) short short8;

__device__ __constant__ int c_H[LEVELS]  = {128, 64, 32, 16};
__device__ __constant__ int c_St[LEVELS] = {0, 16384, 20480, 21504};

template<bool BF>
__device__ __forceinline__ float ldf(const void* p, size_t i) {
  if (BF) return __bfloat162float(((const bf16*)p)[i]);
  else    return ((const float*)p)[i];
}
__device__ __forceinline__ float vt2f(float x) { return x; }
__device__ __forceinline__ float vt2f(bf16 x)  { return __bfloat162float(x); }

// load 4 consecutive elements as float4 (i must be 4-aligned)
template<bool BF>
__device__ __forceinline__ float4 ld4(const void* p, size_t i) {
  if (BF) {
    ushort4 u = *(const ushort4*)((const bf16*)p + i);
    float4 f;
    f.x = __bfloat162float(*reinterpret_cast<bf16*>(&u.x));
    f.y = __bfloat162float(*reinterpret_cast<bf16*>(&u.y));
    f.z = __bfloat162float(*reinterpret_cast<bf16*>(&u.z));
    f.w = __bfloat162float(*reinterpret_cast<bf16*>(&u.w));
    return f;
  } else {
    return *(const float4*)((const float*)p + i);
  }
}

__device__ __forceinline__ void fma4(float4& ac, float s, const float4& wv) {
  ac.x = fmaf(s, wv.x, ac.x);
  ac.y = fmaf(s, wv.y, ac.y);
  ac.z = fmaf(s, wv.z, ac.z);
  ac.w = fmaf(s, wv.w, ac.w);
}

// ---------------------------------------------------------------------------
// Dtype detector (flag=1 -> buffers bf16, flag=0 -> f32). Verbatim.
// ---------------------------------------------------------------------------
__global__ __launch_bounds__(256)
void k_detect(const unsigned short* __restrict__ q16, int* __restrict__ flag) {
  __shared__ int cnt;
  if (threadIdx.x == 0) cnt = 0;
  __syncthreads();
  int c = 0;
  for (int i = threadIdx.x; i < 8192; i += 256) {
    unsigned short v = q16[i];
    if ((v & 0x7F80u) == 0x7F80u) ++c;   // bf16 Inf/NaN pattern
  }
  if (c) atomicAdd(&cnt, c);
  __syncthreads();
  if (threadIdx.x == 0) flag[0] = (cnt == 0) ? 1 : 0;
}

// ---------------------------------------------------------------------------
// shared staging: 16 rows of A (EMBED cols) into padded LDS tile
// ---------------------------------------------------------------------------
template<bool BF>
__device__ __forceinline__ void stage16(const void* __restrict__ A,
                                        float (*rowA)[LDP],
                                        int r0, int M, int t) {
  int r  = t >> 4;                     // 0..15
  int rr = min(r0 + r, M - 1);         // clamp reads; stores guarded later
  int c0 = (t & 15) * 16;              // 0..240
  if (BF) {
    const bf16* ap = (const bf16*)A + (size_t)rr * EMBED + c0;
    short8 a0 = *(const short8*)ap;
    short8 a1 = *(const short8*)(ap + 8);
#pragma unroll
    for (int j = 0; j < 8; ++j) {
      short s0 = a0[j], s1 = a1[j];
      rowA[r][c0 + j]     = __bfloat162float(*reinterpret_cast<bf16*>(&s0));
      rowA[r][c0 + 8 + j] = __bfloat162float(*reinterpret_cast<bf16*>(&s1));
    }
  } else {
    const float* ap = (const float*)A + (size_t)rr * EMBED + c0;
#pragma unroll
    for (int j = 0; j < 4; ++j) {
      float4 f = *(const float4*)(ap + j * 4);
      rowA[r][c0 + j * 4 + 0] = f.x;
      rowA[r][c0 + j * 4 + 1] = f.y;
      rowA[r][c0 + j * 4 + 2] = f.z;
      rowA[r][c0 + j * 4 + 3] = f.w;
    }
  }
}

// ---------------------------------------------------------------------------
// R11: 16-rows/block GEMV, N=256, 4x4 register blocking.
// thread: row-group g = t>>6 (4 rows), cols c0 = (t&63)*4.
// ---------------------------------------------------------------------------
template<bool BF>
__device__ void vgemv4x4_body(const void* __restrict__ A, const void* __restrict__ W,
                              const void* __restrict__ bias, float* __restrict__ C,
                              int M) {
  const int t  = threadIdx.x;
  const int r0 = blockIdx.x * 16;
  if (r0 >= M) return;

  __shared__ float rowA[16][LDP];
  stage16<BF>(A, rowA, r0, M, t);
  __syncthreads();

  const int g  = t >> 6;               // 0..3 (wave-uniform)
  const int c0 = (t & 63) * 4;         // 0..252

  float4 bv;
  bv.x = ldf<BF>(bias, c0 + 0);
  bv.y = ldf<BF>(bias, c0 + 1);
  bv.z = ldf<BF>(bias, c0 + 2);
  bv.w = ldf<BF>(bias, c0 + 3);

  float4 acc[4];
#pragma unroll
  for (int r = 0; r < 4; ++r) acc[r] = bv;

#pragma unroll 2
  for (int k = 0; k < EMBED; k += 4) {
    float4 av[4];
#pragma unroll
    for (int r = 0; r < 4; ++r)
      av[r] = *(const float4*)&rowA[g * 4 + r][k];
    float4 w0 = ld4<BF>(W, (size_t)(k + 0) * EMBED + c0);
    float4 w1 = ld4<BF>(W, (size_t)(k + 1) * EMBED + c0);
    float4 w2 = ld4<BF>(W, (size_t)(k + 2) * EMBED + c0);
    float4 w3 = ld4<BF>(W, (size_t)(k + 3) * EMBED + c0);
#pragma unroll
    for (int r = 0; r < 4; ++r) {
      fma4(acc[r], av[r].x, w0);
      fma4(acc[r], av[r].y, w1);
      fma4(acc[r], av[r].z, w2);
      fma4(acc[r], av[r].w, w3);
    }
  }
#pragma unroll
  for (int r = 0; r < 4; ++r) {
    int row = r0 + g * 4 + r;
    if (row < M) *(float4*)&C[(size_t)row * EMBED + c0] = acc[r];
  }
}

__global__ __launch_bounds__(256)
void k_vgemv4x4(const void* A, const void* W, const void* bias, float* C,
                int M, const int* flag) {
  if (*flag) vgemv4x4_body<true >(A, W, bias, C, M);
  else       vgemv4x4_body<false>(A, W, bias, C, M);
}

// ---------------------------------------------------------------------------
// R11: attn-score GEMV, N=128, 2-row x 4-col blocking.
// thread: row-group g = t>>5 (2 rows), cols c0 = (t&31)*4.
// ---------------------------------------------------------------------------
template<bool BF>
__device__ void agemv4_body(const void* __restrict__ A, const void* __restrict__ W,
                            const void* __restrict__ bias, float* __restrict__ C,
                            int M) {
  const int t  = threadIdx.x;
  const int r0 = blockIdx.x * 16;
  if (r0 >= M) return;

  __shared__ float rowA[16][LDP];
  stage16<BF>(A, rowA, r0, M, t);
  __syncthreads();

  const int g  = t >> 5;               // 0..7 (half-wave 2-way bcast, free)
  const int c0 = (t & 31) * 4;         // 0..124

  float4 bv;
  bv.x = ldf<BF>(bias, c0 + 0);
  bv.y = ldf<BF>(bias, c0 + 1);
  bv.z = ldf<BF>(bias, c0 + 2);
  bv.w = ldf<BF>(bias, c0 + 3);

  float4 acc[2];
  acc[0] = bv; acc[1] = bv;

#pragma unroll 2
  for (int k = 0; k < EMBED; k += 4) {
    float4 a0 = *(const float4*)&rowA[g * 2 + 0][k];
    float4 a1 = *(const float4*)&rowA[g * 2 + 1][k];
    float4 w0 = ld4<BF>(W, (size_t)(k + 0) * 128 + c0);
    float4 w1 = ld4<BF>(W, (size_t)(k + 1) * 128 + c0);
    float4 w2 = ld4<BF>(W, (size_t)(k + 2) * 128 + c0);
    float4 w3 = ld4<BF>(W, (size_t)(k + 3) * 128 + c0);
    fma4(acc[0], a0.x, w0); fma4(acc[0], a0.y, w1);
    fma4(acc[0], a0.z, w2); fma4(acc[0], a0.w, w3);
    fma4(acc[1], a1.x, w0); fma4(acc[1], a1.y, w1);
    fma4(acc[1], a1.z, w2); fma4(acc[1], a1.w, w3);
  }
#pragma unroll
  for (int r = 0; r < 2; ++r) {
    int row = r0 + g * 2 + r;
    if (row < M) *(float4*)&C[(size_t)row * 128 + c0] = acc[r];
  }
}

__global__ __launch_bounds__(256)
void k_agemv4(const void* A, const void* W, const void* bias, float* C,
              int M, const int* flag) {
  if (*flag) agemv4_body<true >(A, W, bias, C, M);
  else       agemv4_body<false>(A, W, bias, C, M);
}

// ---------------------------------------------------------------------------
// R9 k_fused2 (verbatim): softmax + pack (t<128) + ILP-batched gather.
// ---------------------------------------------------------------------------
template<bool BF>
__device__ void fused2_body(const void* __restrict__ ref_points,
                            const float* __restrict__ off_pre,
                            const float* __restrict__ scores,
                            const float* __restrict__ v,
                            void* __restrict__ out, int N, int BN) {
  int q = blockIdx.x;
  if (q >= BN) return;
  int b = q / N;
  int t = threadIdx.x;

  __shared__ float  s_aw[128];
  __shared__ float  s_rp[2];
  __shared__ int4   s_pi[128];   // corner element index (cell<<8)
  __shared__ float4 s_pw[128];   // wa * bilinear * valid

  if (t < 2)   s_rp[t] = ldf<BF>(ref_points, (size_t)q * 2 + t);
  if (t < 128) s_aw[t] = scores[(size_t)q * 128 + t];
  __syncthreads();

  if (t < 128) {
    int base = t & ~15;
    float mx = -1e30f;
#pragma unroll
    for (int i = 0; i < 16; ++i) mx = fmaxf(mx, s_aw[base + i]);
    float sum = 0.f;
#pragma unroll
    for (int i = 0; i < 16; ++i) sum += expf(s_aw[base + i] - mx);
    float wa = expf(s_aw[t] - mx) / sum;

    int   l  = (t >> 2) & 3;
    int   Wl = 128 >> l;                       // levels are square
    float fW = (float)Wl;
    int   st = (int)((65536u - (65536u >> (2 * l))) / 3u);  // level start
    float ox = off_pre[(size_t)q * EMBED + 2 * t]     - 0.5f;
    float oy = off_pre[(size_t)q * EMBED + 2 * t + 1] - 0.5f;
    float x = fmaf(s_rp[0], fW, ox);
    float y = fmaf(s_rp[1], fW, oy);
    float x0f = floorf(x), y0f = floorf(y);
    float lx = x - x0f, ly = y - y0f;
    int x0 = (int)x0f, y0 = (int)y0f;
    int x1 = x0 + 1,   y1 = y0 + 1;
    float w00 = wa * (1.f - lx) * (1.f - ly);
    float w01 = wa * lx * (1.f - ly);
    float w10 = wa * (1.f - lx) * ly;
    float w11 = wa * lx * ly;
    bool vx0 = (unsigned)x0 < (unsigned)Wl;
    bool vx1 = (unsigned)x1 < (unsigned)Wl;
    bool vy0 = (unsigned)y0 < (unsigned)Wl;
    bool vy1 = (unsigned)y1 < (unsigned)Wl;
    int xc0 = min(max(x0, 0), Wl - 1), xc1 = min(max(x1, 0), Wl - 1);
    int yc0 = min(max(y0, 0), Wl - 1), yc1 = min(max(y1, 0), Wl - 1);
    int r0i = st + yc0 * Wl;
    int r1i = st + yc1 * Wl;
    int4 pi; float4 pw;
    pi.x = (r0i + xc0) << 8;  pw.x = (vx0 && vy0) ? w00 : 0.f;
    pi.y = (r0i + xc1) << 8;  pw.y = (vx1 && vy0) ? w01 : 0.f;
    pi.z = (r1i + xc0) << 8;  pw.z = (vx0 && vy1) ? w10 : 0.f;
    pi.w = (r1i + xc1) << 8;  pw.w = (vx1 && vy1) ? w11 : 0.f;
    s_pi[t] = pi;
    s_pw[t] = pw;
  }
  __syncthreads();

  const float* vb = v + (size_t)b * (M_TOT * EMBED);
  const int cb = (t >> 5) << 4;            // h*16
  float o0 = 0.f, o1 = 0.f;
#pragma unroll
  for (int g = 0; g < 4; ++g) {
    const int c0 = cb + (g << 2);
    int4   iA = s_pi[c0 + 0], iB = s_pi[c0 + 1], iC = s_pi[c0 + 2], iD = s_pi[c0 + 3];
    float4 wA = s_pw[c0 + 0], wB = s_pw[c0 + 1], wC = s_pw[c0 + 2], wD = s_pw[c0 + 3];
    float gA0 = vb[iA.x + t], gA1 = vb[iA.y + t], gA2 = vb[iA.z + t], gA3 = vb[iA.w + t];
    float gB0 = vb[iB.x + t], gB1 = vb[iB.y + t], gB2 = vb[iB.z + t], gB3 = vb[iB.w + t];
    float gC0 = vb[iC.x + t], gC1 = vb[iC.y + t], gC2 = vb[iC.z + t], gC3 = vb[iC.w + t];
    float gD0 = vb[iD.x + t], gD1 = vb[iD.y + t], gD2 = vb[iD.z + t], gD3 = vb[iD.w + t];
    o0 = fmaf(wA.x, gA0, o0); o1 = fmaf(wA.y, gA1, o1);
    o0 = fmaf(wA.z, gA2, o0); o1 = fmaf(wA.w, gA3, o1);
    o0 = fmaf(wB.x, gB0, o0); o1 = fmaf(wB.y, gB1, o1);
    o0 = fmaf(wB.z, gB2, o0); o1 = fmaf(wB.w, gB3, o1);
    o0 = fmaf(wC.x, gC0, o0); o1 = fmaf(wC.y, gC1, o1);
    o0 = fmaf(wC.z, gC2, o0); o1 = fmaf(wC.w, gC3, o1);
    o0 = fmaf(wD.x, gD0, o0); o1 = fmaf(wD.y, gD1, o1);
    o0 = fmaf(wD.z, gD2, o0); o1 = fmaf(wD.w, gD3, o1);
  }
  float o = o0 + o1;
  if (BF) ((bf16*)out)[(size_t)q * EMBED + t] = __float2bfloat16(o);
  else    ((float*)out)[(size_t)q * EMBED + t] = o;
}

__global__ __launch_bounds__(256)
void k_fused2(const void* ref_points, const float* off_pre, const float* scores,
              const float* v, void* out, int N, int BN, const int* flag) {
  if (*flag) fused2_body<true >(ref_points, off_pre, scores, v, out, N, BN);
  else       fused2_body<false>(ref_points, off_pre, scores, v, out, N, BN);
}

// ---------------------------------------------------------------------------
// MID TIER (R8, proven): 8-row GEMV + fused with in-kernel attn GEMV.
// ---------------------------------------------------------------------------
template<bool BF>
__device__ void vgemv8_body(const void* __restrict__ A, const void* __restrict__ W,
                            const void* __restrict__ bias, float* __restrict__ C,
                            int M) {
  const int t  = threadIdx.x;
  const int r0 = blockIdx.x * 8;
  if (r0 >= M) return;

  __shared__ float rowA[8][EMBED];
  {
    int r  = t >> 5;
    int rr = min(r0 + r, M - 1);
    int c0 = (t & 31) * 8;
    if (BF) {
      const bf16* ap = (const bf16*)A + (size_t)rr * EMBED + c0;
      short8 a = *(const short8*)ap;
#pragma unroll
      for (int j = 0; j < 8; ++j) {
        short s = a[j];
        bf16 hb = *reinterpret_cast<bf16*>(&s);
        rowA[r][c0 + j] = __bfloat162float(hb);
      }
    } else {
      const float* ap = (const float*)A + (size_t)rr * EMBED + c0;
#pragma unroll
      for (int j = 0; j < 8; ++j) rowA[r][c0 + j] = ap[j];
    }
  }
  __syncthreads();

  const int n = t;
  const float b = ldf<BF>(bias, n);
  float acc[8];
#pragma unroll
  for (int r = 0; r < 8; ++r) acc[r] = b;
#pragma unroll 4
  for (int k = 0; k < EMBED; ++k) {
    float w = ldf<BF>(W, (size_t)k * EMBED + n);
#pragma unroll
    for (int r = 0; r < 8; ++r) acc[r] = fmaf(rowA[r][k], w, acc[r]);
  }
#pragma unroll
  for (int r = 0; r < 8; ++r)
    if (r0 + r < M) C[(size_t)(r0 + r) * EMBED + n] = acc[r];
}

__global__ __launch_bounds__(256)
void k_vgemv8(const void* A, const void* W, const void* bias, float* C,
              int M, const int* flag) {
  if (*flag) vgemv8_body<true >(A, W, bias, C, M);
  else       vgemv8_body<false>(A, W, bias, C, M);
}

template<bool BF, class VT>
__device__ void fused_body(const void* __restrict__ query,
                           const void* __restrict__ ref_points,
                           const float* __restrict__ off_pre,
                           const void* __restrict__ W_attn,
                           const void* __restrict__ b_attn,
                           const VT* __restrict__ v,
                           void* __restrict__ out, int N, int BN) {
  int q = blockIdx.x;
  if (q >= BN) return;
  int b = q / N;
  int t = threadIdx.x;

  __shared__ float  row[EMBED];
  __shared__ float  s_part[256];
  __shared__ float  s_aw[HEADS * LEVELS * POINTS];
  __shared__ float  s_rp[2];
  __shared__ int4   s_pi[HEADS * LEVELS * POINTS];
  __shared__ float4 s_pw[HEADS * LEVELS * POINTS];

  row[t] = ldf<BF>(query, (size_t)q * EMBED + t);
  if (t < 2) s_rp[t] = ldf<BF>(ref_points, (size_t)q * 2 + t);
  __syncthreads();

  {
    const int col = t & 127;
    const int e0  = (t >> 7) * 128;
    float acc = 0.f;
#pragma unroll 8
    for (int e = 0; e < 128; ++e)
      acc = fmaf(row[e0 + e], ldf<BF>(W_attn, (size_t)(e0 + e) * 128 + col), acc);
    s_part[t] = acc;
  }
  __syncthreads();
  if (t < 128)
    s_aw[t] = ldf<BF>(b_attn, t) + s_part[t] + s_part[t + 128];
  __syncthreads();

  if (t < 128) {
    int base = t & ~15;
    float mx = -1e30f;
#pragma unroll
    for (int i = 0; i < 16; ++i) mx = fmaxf(mx, s_aw[base + i]);
    float sum = 0.f;
#pragma unroll
    for (int i = 0; i < 16; ++i) sum += expf(s_aw[base + i] - mx);
    float wa = expf(s_aw[t] - mx) / sum;

    int   l  = (t >> 2) & 3;
    int   Wl = 128 >> l;
    float fW = (float)Wl;
    int   st = (int)((65536u - (65536u >> (2 * l))) / 3u);
    float ox = off_pre[(size_t)q * EMBED + 2 * t]     - 0.5f;
    float oy = off_pre[(size_t)q * EMBED + 2 * t + 1] - 0.5f;
    float x = fmaf(s_rp[0], fW, ox);
    float y = fmaf(s_rp[1], fW, oy);
    float x0f = floorf(x), y0f = floorf(y);
    float lx = x - x0f, ly = y - y0f;
    int x0 = (int)x0f, y0 = (int)y0f;
    int x1 = x0 + 1,   y1 = y0 + 1;
    float w00 = wa * (1.f - lx) * (1.f - ly);
    float w01 = wa * lx * (1.f - ly);
    float w10 = wa * (1.f - lx) * ly;
    float w11 = wa * lx * ly;
    bool vx0 = (unsigned)x0 < (unsigned)Wl;
    bool vx1 = (unsigned)x1 < (unsigned)Wl;
    bool vy0 = (unsigned)y0 < (unsigned)Wl;
    bool vy1 = (unsigned)y1 < (unsigned)Wl;
    int xc0 = min(max(x0, 0), Wl - 1), xc1 = min(max(x1, 0), Wl - 1);
    int yc0 = min(max(y0, 0), Wl - 1), yc1 = min(max(y1, 0), Wl - 1);
    int r0i = st + yc0 * Wl;
    int r1i = st + yc1 * Wl;
    int4 pi; float4 pw;
    pi.x = (r0i + xc0) << 8;  pw.x = (vx0 && vy0) ? w00 : 0.f;
    pi.y = (r0i + xc1) << 8;  pw.y = (vx1 && vy0) ? w01 : 0.f;
    pi.z = (r1i + xc0) << 8;  pw.z = (vx0 && vy1) ? w10 : 0.f;
    pi.w = (r1i + xc1) << 8;  pw.w = (vx1 && vy1) ? w11 : 0.f;
    s_pi[t] = pi;
    s_pw[t] = pw;
  }
  __syncthreads();

  const int h = t >> 5;
  const VT* vbt = v + (size_t)b * M_TOT * EMBED + t;
  float o = 0.f;
#pragma unroll
  for (int lp = 0; lp < 16; ++lp) {
    int c = (h << 4) + lp;
    int4   i4 = s_pi[c];
    float4 w4 = s_pw[c];
    o = fmaf(w4.x, vt2f(vbt[i4.x]), o);
    o = fmaf(w4.y, vt2f(vbt[i4.y]), o);
    o = fmaf(w4.z, vt2f(vbt[i4.z]), o);
    o = fmaf(w4.w, vt2f(vbt[i4.w]), o);
  }
  if (BF) ((bf16*)out)[(size_t)q * EMBED + t] = __float2bfloat16(o);
  else    ((float*)out)[(size_t)q * EMBED + t] = o;
}

template<class VT>
__global__ __launch_bounds__(256)
void k_fused(const void* query, const void* ref_points, const float* off_pre,
             const void* W_attn, const void* b_attn,
             const VT* v, void* out, int N, int BN, const int* flag) {
  if (*flag) fused_body<true,  VT>(query, ref_points, off_pre, W_attn, b_attn, v, out, N, BN);
  else       fused_body<false, VT>(query, ref_points, off_pre, W_attn, b_attn, v, out, N, BN);
}

// ---------------------------------------------------------------------------
// Fallback path (ws too small): R2/R6's bf16 fused path, fully self-contained.
// ---------------------------------------------------------------------------
template<bool BF, class VT>
__device__ void vproj_body(const void* __restrict__ value,
                           const void* __restrict__ W_v,
                           const void* __restrict__ b_v,
                           VT* __restrict__ v, int BM) {
  int m = blockIdx.x;
  if (m >= BM) return;
  int t = threadIdx.x;
  __shared__ float row[EMBED];
  row[t] = ldf<BF>(value, (size_t)m * EMBED + t);
  __syncthreads();
  float acc = ldf<BF>(b_v, t);
#pragma unroll 8
  for (int e = 0; e < EMBED; ++e)
    acc = fmaf(row[e], ldf<BF>(W_v, (size_t)e * EMBED + t), acc);
  if (sizeof(VT) == 2) ((bf16*)v)[(size_t)m * EMBED + t] = __float2bfloat16(acc);
  else                 ((float*)v)[(size_t)m * EMBED + t] = acc;
}

template<class VT>
__global__ __launch_bounds__(256)
void k_value_proj(const void* value, const void* W_v, const void* b_v,
                  VT* v, int BM, const int* flag) {
  if (*flag) vproj_body<true,  VT>(value, W_v, b_v, v, BM);
  else       vproj_body<false, VT>(value, W_v, b_v, v, BM);
}

template<bool BF, class VT>
__device__ void fusedfb_body(const void* __restrict__ query,
                             const void* __restrict__ ref_points,
                             const void* __restrict__ W_off,
                             const void* __restrict__ b_off,
                             const void* __restrict__ W_attn,
                             const void* __restrict__ b_attn,
                             const VT* __restrict__ v,
                             void* __restrict__ out, int N, int BN) {
  int q = blockIdx.x;
  if (q >= BN) return;
  int b = q / N;
  int t = threadIdx.x;

  __shared__ float row[EMBED];
  __shared__ float s_off[EMBED];
  __shared__ float s_aw[HEADS * LEVELS * POINTS];
  __shared__ float s_rp[2];

  row[t] = ldf<BF>(query, (size_t)q * EMBED + t);
  if (t < 2) s_rp[t] = ldf<BF>(ref_points, (size_t)q * 2 + t);
  __syncthreads();

  {
    float acc = ldf<BF>(b_off, t);
#pragma unroll 8
    for (int e = 0; e < EMBED; ++e)
      acc = fmaf(row[e], ldf<BF>(W_off, (size_t)e * EMBED + t), acc);
    s_off[t] = acc;
  }
  if (t < 128) {
    float acc = ldf<BF>(b_attn, t);
#pragma unroll 8
    for (int e = 0; e < EMBED; ++e)
      acc = fmaf(row[e], ldf<BF>(W_attn, (size_t)e * 128 + t), acc);
    s_aw[t] = acc;
  }
  __syncthreads();

  float aval = 0.f;
  if (t < 128) {
    int base = t & ~15;
    float mx = -1e30f;
#pragma unroll
    for (int i = 0; i < 16; ++i) mx = fmaxf(mx, s_aw[base + i]);
    float sum = 0.f;
#pragma unroll
    for (int i = 0; i < 16; ++i) sum += expf(s_aw[base + i] - mx);
    aval = expf(s_aw[t] - mx) / sum;
  }
  __syncthreads();
  if (t < 128) s_aw[t] = aval;
  __syncthreads();

  int h = t >> 5;
  const VT* vb = v + (size_t)b * M_TOT * EMBED;
  float o = 0.f;
#pragma unroll
  for (int l = 0; l < LEVELS; ++l) {
    const int Hl = c_H[l], Wl = c_H[l];
    const VT* vl = vb + (size_t)c_St[l] * EMBED;
    const float fW = (float)Wl, fH = (float)Hl;
#pragma unroll
    for (int p = 0; p < POINTS; ++p) {
      int oi = ((h * LEVELS + l) * POINTS + p) << 1;
      float x = (s_rp[0] + s_off[oi]     / fW) * fW - 0.5f;
      float y = (s_rp[1] + s_off[oi + 1] / fH) * fH - 0.5f;
      float x0f = floorf(x), y0f = floorf(y);
      float lx = x - x0f, ly = y - y0f;
      int x0 = (int)x0f, y0 = (int)y0f;
      float wa = s_aw[(h * LEVELS + l) * POINTS + p];
      float cw[4] = {(1.f - lx) * (1.f - ly), lx * (1.f - ly),
                     (1.f - lx) * ly,         lx * ly};
      const int dxs[4] = {0, 1, 0, 1};
      const int dys[4] = {0, 0, 1, 1};
#pragma unroll
      for (int cidx = 0; cidx < 4; ++cidx) {
        int xi = x0 + dxs[cidx];
        int yi = y0 + dys[cidx];
        bool valid = (xi >= 0) & (xi < Wl) & (yi >= 0) & (yi < Hl);
        int xc = min(max(xi, 0), Wl - 1);
        int yc = min(max(yi, 0), Hl - 1);
        float g = vt2f(vl[(size_t)(yc * Wl + xc) * EMBED + t]);
        o += (valid ? wa * cw[cidx] : 0.f) * g;
      }
    }
  }
  if (BF) ((bf16*)out)[(size_t)q * EMBED + t] = __float2bfloat16(o);
  else    ((float*)out)[(size_t)q * EMBED + t] = o;
}

template<class VT>
__global__ __launch_bounds__(256)
void k_fused_fb(const void* query, const void* ref_points,
                const void* W_off, const void* b_off,
                const void* W_attn, const void* b_attn,
                const VT* v, void* out, int N, int BN, const int* flag) {
  if (*flag) fusedfb_body<true,  VT>(query, ref_points, W_off, b_off, W_attn, b_attn, v, out, N, BN);
  else       fusedfb_body<false, VT>(query, ref_points, W_off, b_off, W_attn, b_attn, v, out, N, BN);
}

// ---------------------------------------------------------------------------
extern "C" void kernel_launch(void* const* d_in, const int* in_sizes, int n_in,
                              void* d_out, int out_size, void* d_ws, size_t ws_size,
                              hipStream_t stream) {
  const void* query      = d_in[0];
  const void* value      = d_in[2];
  const void* ref_points = d_in[3];
  const void* W_off  = d_in[6];
  const void* b_off  = d_in[7];
  const void* W_attn = d_in[8];
  const void* b_attn = d_in[9];
  const void* W_v    = d_in[10];
  const void* b_v    = d_in[11];

  const int BN = in_sizes[0] / EMBED;   // 20000
  const int BM = in_sizes[2] / EMBED;   // 43520
  const int N  = BN / BATCH;

  int*  flag    = (int*)d_ws;
  char* ws_base = (char*)d_ws + 256;

  k_detect<<<1, 256, 0, stream>>>((const unsigned short*)query, flag);

  const size_t sz_v    = (size_t)BM * EMBED * sizeof(float);
  const size_t sz_off  = (size_t)BN * EMBED * sizeof(float);
  const size_t sz_attn = (size_t)BN * 128 * sizeof(float);
  const size_t need_full = 256 + sz_v + sz_off + sz_attn;
  const size_t need_mid  = 256 + sz_v + sz_off;

  if (ws_size >= need_full) {
    float* ws_v    = (float*)ws_base;
    float* ws_off  = (float*)(ws_base + sz_v);
    float* ws_attn = (float*)(ws_base + sz_v + sz_off);
    k_vgemv4x4<<<(BM + 15) / 16, 256, 0, stream>>>(value, W_v, b_v, ws_v, BM, flag);
    k_vgemv4x4<<<(BN + 15) / 16, 256, 0, stream>>>(query, W_off, b_off, ws_off, BN, flag);
    k_agemv4<<<(BN + 15) / 16, 256, 0, stream>>>(query, W_attn, b_attn, ws_attn, BN, flag);
    k_fused2<<<BN, 256, 0, stream>>>(ref_points, ws_off, ws_attn, ws_v,
                                     d_out, N, BN, flag);
  } else if (ws_size >= need_mid) {
    float* ws_v   = (float*)ws_base;
    float* ws_off = (float*)(ws_base + sz_v);
    k_vgemv8<<<(BM + 7) / 8, 256, 0, stream>>>(value, W_v, b_v, ws_v, BM, flag);
    k_vgemv8<<<(BN + 7) / 8, 256, 0, stream>>>(query, W_off, b_off, ws_off, BN, flag);
    k_fused<float><<<BN, 256, 0, stream>>>(query, ref_points, ws_off,
                                           W_attn, b_attn, ws_v, d_out, N, BN, flag);
  } else {
    bf16* ws_v = (bf16*)ws_base;
    k_value_proj<bf16><<<BM, 256, 0, stream>>>(value, W_v, b_v, ws_v, BM, flag);
    k_fused_fb<bf16><<<BN, 256, 0, stream>>>(query, ref_points, W_off, b_off,
                                             W_attn, b_attn, ws_v, d_out, N, BN, flag);
  }
}

// Round 5
// 400.333 us; speedup vs baseline: 1.3931x; 1.0153x over previous
//
#include <hip/hip_runtime.h>
#include <hip/hip_bf16.h>

// DeformableAttention3D — MI355X (gfx950)
// R12: projections moved to MFMA (bf16 path). R11 counters: vproj VALU-bound
// at 38% issue, MfmaUtil 0, occupancy halved by duplicated LDS. The three
// projections are GEMMs -> matrix pipe.
//   * k_transpose_bf16: W -> W^T in ws (320 KB) so B-fragments are k-contiguous.
//   * k_mfma_proj: C[MxN] = A[Mx256] @ W + b, 4 waves/block, wave = 32x64 tile,
//     16x16x32_bf16, no LDS, A/B frags as direct 16B global loads.
//     Layouts: A row=l&15, k=(l>>4)*8+j; B col=l&15, k=(l>>4)*8+j;
//     C col=l&15, row=(l>>4)*4+reg  [guide m89/m162 verified].
//   * flag==0 (f32 inputs): gated R11 VALU kernels run instead.
//   * k_fused2 / lower tiers verbatim from R11.
#define EMBED    256
#define HEADS    8
#define LEVELS   4
#define POINTS   4
#define BATCH    2
#define M_TOT    21760   // 128*128 + 64*64 + 32*32 + 16*16
#define LDP      (EMBED + 4)   // padded LDS leading dim

typedef __hip_bfloat16 bf16;
typedef __attribute__((ext_vector_type(8))) short short8;
typedef __attribute__((ext_vector_type(8))) short bf16x8s;  // 8 bf16 (4 VGPRs)
typedef __attribute__((ext_vector_type(4))) float f32x4;

__device__ __constant__ int c_H[LEVELS]  = {128, 64, 32, 16};
__device__ __constant__ int c_St[LEVELS] = {0, 16384, 20480, 21504};

template<bool BF>
__device__ __forceinline__ float ldf(const void* p, size_t i) {
  if (BF) return __bfloat162float(((const bf16*)p)[i]);
  else    return ((const float*)p)[i];
}
__device__ __forceinline__ float vt2f(float x) { return x; }
__device__ __forceinline__ float vt2f(bf16 x)  { return __bfloat162float(x); }

template<bool BF>
__device__ __forceinline__ float4 ld4(const void* p, size_t i) {
  if (BF) {
    ushort4 u = *(const ushort4*)((const bf16*)p + i);
    float4 f;
    f.x = __bfloat162float(*reinterpret_cast<bf16*>(&u.x));
    f.y = __bfloat162float(*reinterpret_cast<bf16*>(&u.y));
    f.z = __bfloat162float(*reinterpret_cast<bf16*>(&u.z));
    f.w = __bfloat162float(*reinterpret_cast<bf16*>(&u.w));
    return f;
  } else {
    return *(const float4*)((const float*)p + i);
  }
}

__device__ __forceinline__ void fma4(float4& ac, float s, const float4& wv) {
  ac.x = fmaf(s, wv.x, ac.x);
  ac.y = fmaf(s, wv.y, ac.y);
  ac.z = fmaf(s, wv.z, ac.z);
  ac.w = fmaf(s, wv.w, ac.w);
}

// ---------------------------------------------------------------------------
// Dtype detector (flag=1 -> buffers bf16, flag=0 -> f32). Verbatim.
// ---------------------------------------------------------------------------
__global__ __launch_bounds__(256)
void k_detect(const unsigned short* __restrict__ q16, int* __restrict__ flag) {
  __shared__ int cnt;
  if (threadIdx.x == 0) cnt = 0;
  __syncthreads();
  int c = 0;
  for (int i = threadIdx.x; i < 8192; i += 256) {
    unsigned short v = q16[i];
    if ((v & 0x7F80u) == 0x7F80u) ++c;   // bf16 Inf/NaN pattern
  }
  if (c) atomicAdd(&cnt, c);
  __syncthreads();
  if (threadIdx.x == 0) flag[0] = (cnt == 0) ? 1 : 0;
}

// ---------------------------------------------------------------------------
// R12: bf16 transpose  WT[N][K] = W[K][N].  K,N multiples of 64. flag-gated.
// ---------------------------------------------------------------------------
__global__ __launch_bounds__(256)
void k_transpose_bf16(const unsigned short* __restrict__ W,
                      unsigned short* __restrict__ WT,
                      int K, int N, const int* __restrict__ flag) {
  if (*flag != 1) return;
  __shared__ unsigned short tile[64][65];
  const int ntn = N >> 6;
  const int tk = (int)blockIdx.x / ntn;
  const int tn = (int)blockIdx.x % ntn;
  const int k0 = tk << 6, n0 = tn << 6;
  const int t   = threadIdx.x;
  const int row = t >> 2;            // 0..63
  const int cq  = (t & 3) << 4;      // 0,16,32,48
  const unsigned short* src = W + (size_t)(k0 + row) * N + n0 + cq;
#pragma unroll
  for (int j = 0; j < 16; ++j) tile[row][cq + j] = src[j];
  __syncthreads();
  unsigned short* dst = WT + (size_t)(n0 + row) * K + k0 + cq;
#pragma unroll
  for (int j = 0; j < 16; ++j) dst[j] = tile[cq + j][row];
}

// ---------------------------------------------------------------------------
// R12: MFMA projection. C[M x N] = A[M x 256] @ W + bias (W given as WT[N][256],
// all bf16), C f32. Block = 256 thr = 4 waves; block tile 64 rows x 128 cols;
// wave tile 32 x 64 (2 row-frags x 4 col-frags). K-loop 8 x 16x16x32.
// grid.x = ceil(M/64) * (N/128). flag==1 only.
// ---------------------------------------------------------------------------
__global__ __launch_bounds__(256)
void k_mfma_proj(const bf16* __restrict__ A, const bf16* __restrict__ WT,
                 const void* __restrict__ bias, float* __restrict__ C,
                 int M, int N, const int* __restrict__ flag) {
  if (*flag != 1) return;
  const int colBlocks = N >> 7;                  // 2 (N=256) or 1 (N=128)
  const int rb = (int)blockIdx.x / colBlocks;
  const int cb = (int)blockIdx.x % colBlocks;
  const int t   = threadIdx.x;
  const int wid = t >> 6;
  const int l   = t & 63;
  const int lrow = l & 15;                       // A-row / B-col / C-col
  const int lk8  = (l >> 4) << 3;                // k group offset: 0,8,16,24
  const int r0 = rb * 64 + (wid & 1) * 32;
  const int c0 = cb * 128 + (wid >> 1) * 64;

  f32x4 acc[2][4];
#pragma unroll
  for (int rf = 0; rf < 2; ++rf)
#pragma unroll
    for (int cf = 0; cf < 4; ++cf) acc[rf][cf] = (f32x4){0.f, 0.f, 0.f, 0.f};

  const bf16* Ap0 = A + (size_t)min(r0 + lrow,      M - 1) * EMBED + lk8;
  const bf16* Ap1 = A + (size_t)min(r0 + 16 + lrow, M - 1) * EMBED + lk8;
  const bf16* Bp  = WT + (size_t)(c0 + lrow) * EMBED + lk8;

#pragma unroll
  for (int k = 0; k < EMBED; k += 32) {
    bf16x8s a0 = *(const bf16x8s*)(Ap0 + k);
    bf16x8s a1 = *(const bf16x8s*)(Ap1 + k);
    bf16x8s b0 = *(const bf16x8s*)(Bp + 0 * 16 * EMBED + k);
    bf16x8s b1 = *(const bf16x8s*)(Bp + 1 * 16 * EMBED + k);
    bf16x8s b2 = *(const bf16x8s*)(Bp + 2 * 16 * EMBED + k);
    bf16x8s b3 = *(const bf16x8s*)(Bp + 3 * 16 * EMBED + k);
    acc[0][0] = __builtin_amdgcn_mfma_f32_16x16x32_bf16(a0, b0, acc[0][0], 0, 0, 0);
    acc[0][1] = __builtin_amdgcn_mfma_f32_16x16x32_bf16(a0, b1, acc[0][1], 0, 0, 0);
    acc[0][2] = __builtin_amdgcn_mfma_f32_16x16x32_bf16(a0, b2, acc[0][2], 0, 0, 0);
    acc[0][3] = __builtin_amdgcn_mfma_f32_16x16x32_bf16(a0, b3, acc[0][3], 0, 0, 0);
    acc[1][0] = __builtin_amdgcn_mfma_f32_16x16x32_bf16(a1, b0, acc[1][0], 0, 0, 0);
    acc[1][1] = __builtin_amdgcn_mfma_f32_16x16x32_bf16(a1, b1, acc[1][1], 0, 0, 0);
    acc[1][2] = __builtin_amdgcn_mfma_f32_16x16x32_bf16(a1, b2, acc[1][2], 0, 0, 0);
    acc[1][3] = __builtin_amdgcn_mfma_f32_16x16x32_bf16(a1, b3, acc[1][3], 0, 0, 0);
  }

  const int rbase = (l >> 4) << 2;               // C row sub-offset
#pragma unroll
  for (int cf = 0; cf < 4; ++cf) {
    const int col = c0 + cf * 16 + lrow;
    const float bv = ldf<true>(bias, col);
#pragma unroll
    for (int rf = 0; rf < 2; ++rf) {
#pragma unroll
      for (int r = 0; r < 4; ++r) {
        const int row = r0 + rf * 16 + rbase + r;
        if (row < M) C[(size_t)row * N + col] = acc[rf][cf][r] + bv;
      }
    }
  }
}

// ---------------------------------------------------------------------------
// shared staging: 16 rows of A (EMBED cols) into padded LDS tile (R11)
// ---------------------------------------------------------------------------
template<bool BF>
__device__ __forceinline__ void stage16(const void* __restrict__ A,
                                        float (*rowA)[LDP],
                                        int r0, int M, int t) {
  int r  = t >> 4;                     // 0..15
  int rr = min(r0 + r, M - 1);         // clamp reads; stores guarded later
  int c0 = (t & 15) * 16;              // 0..240
  if (BF) {
    const bf16* ap = (const bf16*)A + (size_t)rr * EMBED + c0;
    short8 a0 = *(const short8*)ap;
    short8 a1 = *(const short8*)(ap + 8);
#pragma unroll
    for (int j = 0; j < 8; ++j) {
      short s0 = a0[j], s1 = a1[j];
      rowA[r][c0 + j]     = __bfloat162float(*reinterpret_cast<bf16*>(&s0));
      rowA[r][c0 + 8 + j] = __bfloat162float(*reinterpret_cast<bf16*>(&s1));
    }
  } else {
    const float* ap = (const float*)A + (size_t)rr * EMBED + c0;
#pragma unroll
    for (int j = 0; j < 4; ++j) {
      float4 f = *(const float4*)(ap + j * 4);
      rowA[r][c0 + j * 4 + 0] = f.x;
      rowA[r][c0 + j * 4 + 1] = f.y;
      rowA[r][c0 + j * 4 + 2] = f.z;
      rowA[r][c0 + j * 4 + 3] = f.w;
    }
  }
}

// ---------------------------------------------------------------------------
// R11: 16-rows/block GEMV, N=256, 4x4 register blocking.
// ---------------------------------------------------------------------------
template<bool BF>
__device__ void vgemv4x4_body(const void* __restrict__ A, const void* __restrict__ W,
                              const void* __restrict__ bias, float* __restrict__ C,
                              int M) {
  const int t  = threadIdx.x;
  const int r0 = blockIdx.x * 16;
  if (r0 >= M) return;

  __shared__ float rowA[16][LDP];
  stage16<BF>(A, rowA, r0, M, t);
  __syncthreads();

  const int g  = t >> 6;               // 0..3 (wave-uniform)
  const int c0 = (t & 63) * 4;         // 0..252

  float4 bv;
  bv.x = ldf<BF>(bias, c0 + 0);
  bv.y = ldf<BF>(bias, c0 + 1);
  bv.z = ldf<BF>(bias, c0 + 2);
  bv.w = ldf<BF>(bias, c0 + 3);

  float4 acc[4];
#pragma unroll
  for (int r = 0; r < 4; ++r) acc[r] = bv;

#pragma unroll 2
  for (int k = 0; k < EMBED; k += 4) {
    float4 av[4];
#pragma unroll
    for (int r = 0; r < 4; ++r)
      av[r] = *(const float4*)&rowA[g * 4 + r][k];
    float4 w0 = ld4<BF>(W, (size_t)(k + 0) * EMBED + c0);
    float4 w1 = ld4<BF>(W, (size_t)(k + 1) * EMBED + c0);
    float4 w2 = ld4<BF>(W, (size_t)(k + 2) * EMBED + c0);
    float4 w3 = ld4<BF>(W, (size_t)(k + 3) * EMBED + c0);
#pragma unroll
    for (int r = 0; r < 4; ++r) {
      fma4(acc[r], av[r].x, w0);
      fma4(acc[r], av[r].y, w1);
      fma4(acc[r], av[r].z, w2);
      fma4(acc[r], av[r].w, w3);
    }
  }
#pragma unroll
  for (int r = 0; r < 4; ++r) {
    int row = r0 + g * 4 + r;
    if (row < M) *(float4*)&C[(size_t)row * EMBED + c0] = acc[r];
  }
}

__global__ __launch_bounds__(256)
void k_vgemv4x4(const void* A, const void* W, const void* bias, float* C,
                int M, const int* flag) {
  if (*flag) vgemv4x4_body<true >(A, W, bias, C, M);
  else       vgemv4x4_body<false>(A, W, bias, C, M);
}

// f32-only gated variant (mfma tier fallback when inputs are f32)
__global__ __launch_bounds__(256)
void k_vgemv4x4_f32only(const void* A, const void* W, const void* bias, float* C,
                        int M, const int* flag) {
  if (*flag == 0) vgemv4x4_body<false>(A, W, bias, C, M);
}

// ---------------------------------------------------------------------------
// R11: attn-score GEMV, N=128, 2-row x 4-col blocking.
// ---------------------------------------------------------------------------
template<bool BF>
__device__ void agemv4_body(const void* __restrict__ A, const void* __restrict__ W,
                            const void* __restrict__ bias, float* __restrict__ C,
                            int M) {
  const int t  = threadIdx.x;
  const int r0 = blockIdx.x * 16;
  if (r0 >= M) return;

  __shared__ float rowA[16][LDP];
  stage16<BF>(A, rowA, r0, M, t);
  __syncthreads();

  const int g  = t >> 5;               // 0..7
  const int c0 = (t & 31) * 4;         // 0..124

  float4 bv;
  bv.x = ldf<BF>(bias, c0 + 0);
  bv.y = ldf<BF>(bias, c0 + 1);
  bv.z = ldf<BF>(bias, c0 + 2);
  bv.w = ldf<BF>(bias, c0 + 3);

  float4 acc[2];
  acc[0] = bv; acc[1] = bv;

#pragma unroll 2
  for (int k = 0; k < EMBED; k += 4) {
    float4 a0 = *(const float4*)&rowA[g * 2 + 0][k];
    float4 a1 = *(const float4*)&rowA[g * 2 + 1][k];
    float4 w0 = ld4<BF>(W, (size_t)(k + 0) * 128 + c0);
    float4 w1 = ld4<BF>(W, (size_t)(k + 1) * 128 + c0);
    float4 w2 = ld4<BF>(W, (size_t)(k + 2) * 128 + c0);
    float4 w3 = ld4<BF>(W, (size_t)(k + 3) * 128 + c0);
    fma4(acc[0], a0.x, w0); fma4(acc[0], a0.y, w1);
    fma4(acc[0], a0.z, w2); fma4(acc[0], a0.w, w3);
    fma4(acc[1], a1.x, w0); fma4(acc[1], a1.y, w1);
    fma4(acc[1], a1.z, w2); fma4(acc[1], a1.w, w3);
  }
#pragma unroll
  for (int r = 0; r < 2; ++r) {
    int row = r0 + g * 2 + r;
    if (row < M) *(float4*)&C[(size_t)row * 128 + c0] = acc[r];
  }
}

__global__ __launch_bounds__(256)
void k_agemv4(const void* A, const void* W, const void* bias, float* C,
              int M, const int* flag) {
  if (*flag) agemv4_body<true >(A, W, bias, C, M);
  else       agemv4_body<false>(A, W, bias, C, M);
}

__global__ __launch_bounds__(256)
void k_agemv4_f32only(const void* A, const void* W, const void* bias, float* C,
                      int M, const int* flag) {
  if (*flag == 0) agemv4_body<false>(A, W, bias, C, M);
}

// ---------------------------------------------------------------------------
// R9 k_fused2 (verbatim): softmax + pack (t<128) + ILP-batched gather.
// ---------------------------------------------------------------------------
template<bool BF>
__device__ void fused2_body(const void* __restrict__ ref_points,
                            const float* __restrict__ off_pre,
                            const float* __restrict__ scores,
                            const float* __restrict__ v,
                            void* __restrict__ out, int N, int BN) {
  int q = blockIdx.x;
  if (q >= BN) return;
  int b = q / N;
  int t = threadIdx.x;

  __shared__ float  s_aw[128];
  __shared__ float  s_rp[2];
  __shared__ int4   s_pi[128];   // corner element index (cell<<8)
  __shared__ float4 s_pw[128];   // wa * bilinear * valid

  if (t < 2)   s_rp[t] = ldf<BF>(ref_points, (size_t)q * 2 + t);
  if (t < 128) s_aw[t] = scores[(size_t)q * 128 + t];
  __syncthreads();

  if (t < 128) {
    int base = t & ~15;
    float mx = -1e30f;
#pragma unroll
    for (int i = 0; i < 16; ++i) mx = fmaxf(mx, s_aw[base + i]);
    float sum = 0.f;
#pragma unroll
    for (int i = 0; i < 16; ++i) sum += expf(s_aw[base + i] - mx);
    float wa = expf(s_aw[t] - mx) / sum;

    int   l  = (t >> 2) & 3;
    int   Wl = 128 >> l;                       // levels are square
    float fW = (float)Wl;
    int   st = (int)((65536u - (65536u >> (2 * l))) / 3u);  // level start
    float ox = off_pre[(size_t)q * EMBED + 2 * t]     - 0.5f;
    float oy = off_pre[(size_t)q * EMBED + 2 * t + 1] - 0.5f;
    float x = fmaf(s_rp[0], fW, ox);
    float y = fmaf(s_rp[1], fW, oy);
    float x0f = floorf(x), y0f = floorf(y);
    float lx = x - x0f, ly = y - y0f;
    int x0 = (int)x0f, y0 = (int)y0f;
    int x1 = x0 + 1,   y1 = y0 + 1;
    float w00 = wa * (1.f - lx) * (1.f - ly);
    float w01 = wa * lx * (1.f - ly);
    float w10 = wa * (1.f - lx) * ly;
    float w11 = wa * lx * ly;
    bool vx0 = (unsigned)x0 < (unsigned)Wl;
    bool vx1 = (unsigned)x1 < (unsigned)Wl;
    bool vy0 = (unsigned)y0 < (unsigned)Wl;
    bool vy1 = (unsigned)y1 < (unsigned)Wl;
    int xc0 = min(max(x0, 0), Wl - 1), xc1 = min(max(x1, 0), Wl - 1);
    int yc0 = min(max(y0, 0), Wl - 1), yc1 = min(max(y1, 0), Wl - 1);
    int r0i = st + yc0 * Wl;
    int r1i = st + yc1 * Wl;
    int4 pi; float4 pw;
    pi.x = (r0i + xc0) << 8;  pw.x = (vx0 && vy0) ? w00 : 0.f;
    pi.y = (r0i + xc1) << 8;  pw.y = (vx1 && vy0) ? w01 : 0.f;
    pi.z = (r1i + xc0) << 8;  pw.z = (vx0 && vy1) ? w10 : 0.f;
    pi.w = (r1i + xc1) << 8;  pw.w = (vx1 && vy1) ? w11 : 0.f;
    s_pi[t] = pi;
    s_pw[t] = pw;
  }
  __syncthreads();

  const float* vb = v + (size_t)b * (M_TOT * EMBED);
  const int cb = (t >> 5) << 4;            // h*16
  float o0 = 0.f, o1 = 0.f;
#pragma unroll
  for (int g = 0; g < 4; ++g) {
    const int c0 = cb + (g << 2);
    int4   iA = s_pi[c0 + 0], iB = s_pi[c0 + 1], iC = s_pi[c0 + 2], iD = s_pi[c0 + 3];
    float4 wA = s_pw[c0 + 0], wB = s_pw[c0 + 1], wC = s_pw[c0 + 2], wD = s_pw[c0 + 3];
    float gA0 = vb[iA.x + t], gA1 = vb[iA.y + t], gA2 = vb[iA.z + t], gA3 = vb[iA.w + t];
    float gB0 = vb[iB.x + t], gB1 = vb[iB.y + t], gB2 = vb[iB.z + t], gB3 = vb[iB.w + t];
    float gC0 = vb[iC.x + t], gC1 = vb[iC.y + t], gC2 = vb[iC.z + t], gC3 = vb[iC.w + t];
    float gD0 = vb[iD.x + t], gD1 = vb[iD.y + t], gD2 = vb[iD.z + t], gD3 = vb[iD.w + t];
    o0 = fmaf(wA.x, gA0, o0); o1 = fmaf(wA.y, gA1, o1);
    o0 = fmaf(wA.z, gA2, o0); o1 = fmaf(wA.w, gA3, o1);
    o0 = fmaf(wB.x, gB0, o0); o1 = fmaf(wB.y, gB1, o1);
    o0 = fmaf(wB.z, gB2, o0); o1 = fmaf(wB.w, gB3, o1);
    o0 = fmaf(wC.x, gC0, o0); o1 = fmaf(wC.y, gC1, o1);
    o0 = fmaf(wC.z, gC2, o0); o1 = fmaf(wC.w, gC3, o1);
    o0 = fmaf(wD.x, gD0, o0); o1 = fmaf(wD.y, gD1, o1);
    o0 = fmaf(wD.z, gD2, o0); o1 = fmaf(wD.w, gD3, o1);
  }
  float o = o0 + o1;
  if (BF) ((bf16*)out)[(size_t)q * EMBED + t] = __float2bfloat16(o);
  else    ((float*)out)[(size_t)q * EMBED + t] = o;
}

__global__ __launch_bounds__(256)
void k_fused2(const void* ref_points, const float* off_pre, const float* scores,
              const float* v, void* out, int N, int BN, const int* flag) {
  if (*flag) fused2_body<true >(ref_points, off_pre, scores, v, out, N, BN);
  else       fused2_body<false>(ref_points, off_pre, scores, v, out, N, BN);
}

// ---------------------------------------------------------------------------
// MID TIER (R8, proven): 8-row GEMV + fused with in-kernel attn GEMV.
// ---------------------------------------------------------------------------
template<bool BF>
__device__ void vgemv8_body(const void* __restrict__ A, const void* __restrict__ W,
                            const void* __restrict__ bias, float* __restrict__ C,
                            int M) {
  const int t  = threadIdx.x;
  const int r0 = blockIdx.x * 8;
  if (r0 >= M) return;

  __shared__ float rowA[8][EMBED];
  {
    int r  = t >> 5;
    int rr = min(r0 + r, M - 1);
    int c0 = (t & 31) * 8;
    if (BF) {
      const bf16* ap = (const bf16*)A + (size_t)rr * EMBED + c0;
      short8 a = *(const short8*)ap;
#pragma unroll
      for (int j = 0; j < 8; ++j) {
        short s = a[j];
        bf16 hb = *reinterpret_cast<bf16*>(&s);
        rowA[r][c0 + j] = __bfloat162float(hb);
      }
    } else {
      const float* ap = (const float*)A + (size_t)rr * EMBED + c0;
#pragma unroll
      for (int j = 0; j < 8; ++j) rowA[r][c0 + j] = ap[j];
    }
  }
  __syncthreads();

  const int n = t;
  const float b = ldf<BF>(bias, n);
  float acc[8];
#pragma unroll
  for (int r = 0; r < 8; ++r) acc[r] = b;
#pragma unroll 4
  for (int k = 0; k < EMBED; ++k) {
    float w = ldf<BF>(W, (size_t)k * EMBED + n);
#pragma unroll
    for (int r = 0; r < 8; ++r) acc[r] = fmaf(rowA[r][k], w, acc[r]);
  }
#pragma unroll
  for (int r = 0; r < 8; ++r)
    if (r0 + r < M) C[(size_t)(r0 + r) * EMBED + n] = acc[r];
}

__global__ __launch_bounds__(256)
void k_vgemv8(const void* A, const void* W, const void* bias, float* C,
              int M, const int* flag) {
  if (*flag) vgemv8_body<true >(A, W, bias, C, M);
  else       vgemv8_body<false>(A, W, bias, C, M);
}

template<bool BF, class VT>
__device__ void fused_body(const void* __restrict__ query,
                           const void* __restrict__ ref_points,
                           const float* __restrict__ off_pre,
                           const void* __restrict__ W_attn,
                           const void* __restrict__ b_attn,
                           const VT* __restrict__ v,
                           void* __restrict__ out, int N, int BN) {
  int q = blockIdx.x;
  if (q >= BN) return;
  int b = q / N;
  int t = threadIdx.x;

  __shared__ float  row[EMBED];
  __shared__ float  s_part[256];
  __shared__ float  s_aw[HEADS * LEVELS * POINTS];
  __shared__ float  s_rp[2];
  __shared__ int4   s_pi[HEADS * LEVELS * POINTS];
  __shared__ float4 s_pw[HEADS * LEVELS * POINTS];

  row[t] = ldf<BF>(query, (size_t)q * EMBED + t);
  if (t < 2) s_rp[t] = ldf<BF>(ref_points, (size_t)q * 2 + t);
  __syncthreads();

  {
    const int col = t & 127;
    const int e0  = (t >> 7) * 128;
    float acc = 0.f;
#pragma unroll 8
    for (int e = 0; e < 128; ++e)
      acc = fmaf(row[e0 + e], ldf<BF>(W_attn, (size_t)(e0 + e) * 128 + col), acc);
    s_part[t] = acc;
  }
  __syncthreads();
  if (t < 128)
    s_aw[t] = ldf<BF>(b_attn, t) + s_part[t] + s_part[t + 128];
  __syncthreads();

  if (t < 128) {
    int base = t & ~15;
    float mx = -1e30f;
#pragma unroll
    for (int i = 0; i < 16; ++i) mx = fmaxf(mx, s_aw[base + i]);
    float sum = 0.f;
#pragma unroll
    for (int i = 0; i < 16; ++i) sum += expf(s_aw[base + i] - mx);
    float wa = expf(s_aw[t] - mx) / sum;

    int   l  = (t >> 2) & 3;
    int   Wl = 128 >> l;
    float fW = (float)Wl;
    int   st = (int)((65536u - (65536u >> (2 * l))) / 3u);
    float ox = off_pre[(size_t)q * EMBED + 2 * t]     - 0.5f;
    float oy = off_pre[(size_t)q * EMBED + 2 * t + 1] - 0.5f;
    float x = fmaf(s_rp[0], fW, ox);
    float y = fmaf(s_rp[1], fW, oy);
    float x0f = floorf(x), y0f = floorf(y);
    float lx = x - x0f, ly = y - y0f;
    int x0 = (int)x0f, y0 = (int)y0f;
    int x1 = x0 + 1,   y1 = y0 + 1;
    float w00 = wa * (1.f - lx) * (1.f - ly);
    float w01 = wa * lx * (1.f - ly);
    float w10 = wa * (1.f - lx) * ly;
    float w11 = wa * lx * ly;
    bool vx0 = (unsigned)x0 < (unsigned)Wl;
    bool vx1 = (unsigned)x1 < (unsigned)Wl;
    bool vy0 = (unsigned)y0 < (unsigned)Wl;
    bool vy1 = (unsigned)y1 < (unsigned)Wl;
    int xc0 = min(max(x0, 0), Wl - 1), xc1 = min(max(x1, 0), Wl - 1);
    int yc0 = min(max(y0, 0), Wl - 1), yc1 = min(max(y1, 0), Wl - 1);
    int r0i = st + yc0 * Wl;
    int r1i = st + yc1 * Wl;
    int4 pi; float4 pw;
    pi.x = (r0i + xc0) << 8;  pw.x = (vx0 && vy0) ? w00 : 0.f;
    pi.y = (r0i + xc1) << 8;  pw.y = (vx1 && vy0) ? w01 : 0.f;
    pi.z = (r1i + xc0) << 8;  pw.z = (vx0 && vy1) ? w10 : 0.f;
    pi.w = (r1i + xc1) << 8;  pw.w = (vx1 && vy1) ? w11 : 0.f;
    s_pi[t] = pi;
    s_pw[t] = pw;
  }
  __syncthreads();

  const int h = t >> 5;
  const VT* vbt = v + (size_t)b * M_TOT * EMBED + t;
  float o = 0.f;
#pragma unroll
  for (int lp = 0; lp < 16; ++lp) {
    int c = (h << 4) + lp;
    int4   i4 = s_pi[c];
    float4 w4 = s_pw[c];
    o = fmaf(w4.x, vt2f(vbt[i4.x]), o);
    o = fmaf(w4.y, vt2f(vbt[i4.y]), o);
    o = fmaf(w4.z, vt2f(vbt[i4.z]), o);
    o = fmaf(w4.w, vt2f(vbt[i4.w]), o);
  }
  if (BF) ((bf16*)out)[(size_t)q * EMBED + t] = __float2bfloat16(o);
  else    ((float*)out)[(size_t)q * EMBED + t] = o;
}

template<class VT>
__global__ __launch_bounds__(256)
void k_fused(const void* query, const void* ref_points, const float* off_pre,
             const void* W_attn, const void* b_attn,
             const VT* v, void* out, int N, int BN, const int* flag) {
  if (*flag) fused_body<true,  VT>(query, ref_points, off_pre, W_attn, b_attn, v, out, N, BN);
  else       fused_body<false, VT>(query, ref_points, off_pre, W_attn, b_attn, v, out, N, BN);
}

// ---------------------------------------------------------------------------
// Fallback path (ws too small): R2/R6's bf16 fused path, fully self-contained.
// ---------------------------------------------------------------------------
template<bool BF, class VT>
__device__ void vproj_body(const void* __restrict__ value,
                           const void* __restrict__ W_v,
                           const void* __restrict__ b_v,
                           VT* __restrict__ v, int BM) {
  int m = blockIdx.x;
  if (m >= BM) return;
  int t = threadIdx.x;
  __shared__ float row[EMBED];
  row[t] = ldf<BF>(value, (size_t)m * EMBED + t);
  __syncthreads();
  float acc = ldf<BF>(b_v, t);
#pragma unroll 8
  for (int e = 0; e < EMBED; ++e)
    acc = fmaf(row[e], ldf<BF>(W_v, (size_t)e * EMBED + t), acc);
  if (sizeof(VT) == 2) ((bf16*)v)[(size_t)m * EMBED + t] = __float2bfloat16(acc);
  else                 ((float*)v)[(size_t)m * EMBED + t] = acc;
}

template<class VT>
__global__ __launch_bounds__(256)
void k_value_proj(const void* value, const void* W_v, const void* b_v,
                  VT* v, int BM, const int* flag) {
  if (*flag) vproj_body<true,  VT>(value, W_v, b_v, v, BM);
  else       vproj_body<false, VT>(value, W_v, b_v, v, BM);
}

template<bool BF, class VT>
__device__ void fusedfb_body(const void* __restrict__ query,
                             const void* __restrict__ ref_points,
                             const void* __restrict__ W_off,
                             const void* __restrict__ b_off,
                             const void* __restrict__ W_attn,
                             const void* __restrict__ b_attn,
                             const VT* __restrict__ v,
                             void* __restrict__ out, int N, int BN) {
  int q = blockIdx.x;
  if (q >= BN) return;
  int b = q / N;
  int t = threadIdx.x;

  __shared__ float row[EMBED];
  __shared__ float s_off[EMBED];
  __shared__ float s_aw[HEADS * LEVELS * POINTS];
  __shared__ float s_rp[2];

  row[t] = ldf<BF>(query, (size_t)q * EMBED + t);
  if (t < 2) s_rp[t] = ldf<BF>(ref_points, (size_t)q * 2 + t);
  __syncthreads();

  {
    float acc = ldf<BF>(b_off, t);
#pragma unroll 8
    for (int e = 0; e < EMBED; ++e)
      acc = fmaf(row[e], ldf<BF>(W_off, (size_t)e * EMBED + t), acc);
    s_off[t] = acc;
  }
  if (t < 128) {
    float acc = ldf<BF>(b_attn, t);
#pragma unroll 8
    for (int e = 0; e < EMBED; ++e)
      acc = fmaf(row[e], ldf<BF>(W_attn, (size_t)e * 128 + t), acc);
    s_aw[t] = acc;
  }
  __syncthreads();

  float aval = 0.f;
  if (t < 128) {
    int base = t & ~15;
    float mx = -1e30f;
#pragma unroll
    for (int i = 0; i < 16; ++i) mx = fmaxf(mx, s_aw[base + i]);
    float sum = 0.f;
#pragma unroll
    for (int i = 0; i < 16; ++i) sum += expf(s_aw[base + i] - mx);
    aval = expf(s_aw[t] - mx) / sum;
  }
  __syncthreads();
  if (t < 128) s_aw[t] = aval;
  __syncthreads();

  int h = t >> 5;
  const VT* vb = v + (size_t)b * M_TOT * EMBED;
  float o = 0.f;
#pragma unroll
  for (int l = 0; l < LEVELS; ++l) {
    const int Hl = c_H[l], Wl = c_H[l];
    const VT* vl = vb + (size_t)c_St[l] * EMBED;
    const float fW = (float)Wl, fH = (float)Hl;
#pragma unroll
    for (int p = 0; p < POINTS; ++p) {
      int oi = ((h * LEVELS + l) * POINTS + p) << 1;
      float x = (s_rp[0] + s_off[oi]     / fW) * fW - 0.5f;
      float y = (s_rp[1] + s_off[oi + 1] / fH) * fH - 0.5f;
      float x0f = floorf(x), y0f = floorf(y);
      float lx = x - x0f, ly = y - y0f;
      int x0 = (int)x0f, y0 = (int)y0f;
      float wa = s_aw[(h * LEVELS + l) * POINTS + p];
      float cw[4] = {(1.f - lx) * (1.f - ly), lx * (1.f - ly),
                     (1.f - lx) * ly,         lx * ly};
      const int dxs[4] = {0, 1, 0, 1};
      const int dys[4] = {0, 0, 1, 1};
#pragma unroll
      for (int cidx = 0; cidx < 4; ++cidx) {
        int xi = x0 + dxs[cidx];
        int yi = y0 + dys[cidx];
        bool valid = (xi >= 0) & (xi < Wl) & (yi >= 0) & (yi < Hl);
        int xc = min(max(xi, 0), Wl - 1);
        int yc = min(max(yi, 0), Hl - 1);
        float g = vt2f(vl[(size_t)(yc * Wl + xc) * EMBED + t]);
        o += (valid ? wa * cw[cidx] : 0.f) * g;
      }
    }
  }
  if (BF) ((bf16*)out)[(size_t)q * EMBED + t] = __float2bfloat16(o);
  else    ((float*)out)[(size_t)q * EMBED + t] = o;
}

template<class VT>
__global__ __launch_bounds__(256)
void k_fused_fb(const void* query, const void* ref_points,
                const void* W_off, const void* b_off,
                const void* W_attn, const void* b_attn,
                const VT* v, void* out, int N, int BN, const int* flag) {
  if (*flag) fusedfb_body<true,  VT>(query, ref_points, W_off, b_off, W_attn, b_attn, v, out, N, BN);
  else       fusedfb_body<false, VT>(query, ref_points, W_off, b_off, W_attn, b_attn, v, out, N, BN);
}

// ---------------------------------------------------------------------------
extern "C" void kernel_launch(void* const* d_in, const int* in_sizes, int n_in,
                              void* d_out, int out_size, void* d_ws, size_t ws_size,
                              hipStream_t stream) {
  const void* query      = d_in[0];
  const void* value      = d_in[2];
  const void* ref_points = d_in[3];
  const void* W_off  = d_in[6];
  const void* b_off  = d_in[7];
  const void* W_attn = d_in[8];
  const void* b_attn = d_in[9];
  const void* W_v    = d_in[10];
  const void* b_v    = d_in[11];

  const int BN = in_sizes[0] / EMBED;   // 20000
  const int BM = in_sizes[2] / EMBED;   // 43520
  const int N  = BN / BATCH;

  int*  flag    = (int*)d_ws;
  char* ws_base = (char*)d_ws + 256;

  k_detect<<<1, 256, 0, stream>>>((const unsigned short*)query, flag);

  const size_t sz_v    = (size_t)BM * EMBED * sizeof(float);
  const size_t sz_off  = (size_t)BN * EMBED * sizeof(float);
  const size_t sz_attn = (size_t)BN * 128 * sizeof(float);
  const size_t sz_T    = (size_t)(256 * 256 + 256 * 256 + 256 * 128) * 2; // 320KB
  const size_t need_mfma = 256 + sz_v + sz_off + sz_attn + sz_T;
  const size_t need_full = 256 + sz_v + sz_off + sz_attn;
  const size_t need_mid  = 256 + sz_v + sz_off;

  if (ws_size >= need_mfma) {
    float* ws_v    = (float*)ws_base;
    float* ws_off  = (float*)(ws_base + sz_v);
    float* ws_attn = (float*)(ws_base + sz_v + sz_off);
    unsigned short* wsT      = (unsigned short*)(ws_base + sz_v + sz_off + sz_attn);
    unsigned short* wsT_v    = wsT;
    unsigned short* wsT_off  = wsT + 256 * 256;
    unsigned short* wsT_attn = wsT + 2 * 256 * 256;

    // bf16 path (flag==1): transpose weights, then MFMA projections
    k_transpose_bf16<<<16, 256, 0, stream>>>((const unsigned short*)W_v,    wsT_v,    256, 256, flag);
    k_transpose_bf16<<<16, 256, 0, stream>>>((const unsigned short*)W_off,  wsT_off,  256, 256, flag);
    k_transpose_bf16<<< 8, 256, 0, stream>>>((const unsigned short*)W_attn, wsT_attn, 256, 128, flag);
    const int rbV = (BM + 63) / 64;   // 680
    const int rbQ = (BN + 63) / 64;   // 313
    k_mfma_proj<<<rbV * 2, 256, 0, stream>>>((const bf16*)value, (const bf16*)wsT_v,
                                             b_v, ws_v, BM, 256, flag);
    k_mfma_proj<<<rbQ * 2, 256, 0, stream>>>((const bf16*)query, (const bf16*)wsT_off,
                                             b_off, ws_off, BN, 256, flag);
    k_mfma_proj<<<rbQ,     256, 0, stream>>>((const bf16*)query, (const bf16*)wsT_attn,
                                             b_attn, ws_attn, BN, 128, flag);
    // f32 path (flag==0): proven VALU kernels, gated
    k_vgemv4x4_f32only<<<(BM + 15) / 16, 256, 0, stream>>>(value, W_v, b_v, ws_v, BM, flag);
    k_vgemv4x4_f32only<<<(BN + 15) / 16, 256, 0, stream>>>(query, W_off, b_off, ws_off, BN, flag);
    k_agemv4_f32only  <<<(BN + 15) / 16, 256, 0, stream>>>(query, W_attn, b_attn, ws_attn, BN, flag);

    k_fused2<<<BN, 256, 0, stream>>>(ref_points, ws_off, ws_attn, ws_v,
                                     d_out, N, BN, flag);
  } else if (ws_size >= need_full) {
    float* ws_v    = (float*)ws_base;
    float* ws_off  = (float*)(ws_base + sz_v);
    float* ws_attn = (float*)(ws_base + sz_v + sz_off);
    k_vgemv4x4<<<(BM + 15) / 16, 256, 0, stream>>>(value, W_v, b_v, ws_v, BM, flag);
    k_vgemv4x4<<<(BN + 15) / 16, 256, 0, stream>>>(query, W_off, b_off, ws_off, BN, flag);
    k_agemv4<<<(BN + 15) / 16, 256, 0, stream>>>(query, W_attn, b_attn, ws_attn, BN, flag);
    k_fused2<<<BN, 256, 0, stream>>>(ref_points, ws_off, ws_attn, ws_v,
                                     d_out, N, BN, flag);
  } else if (ws_size >= need_mid) {
    float* ws_v   = (float*)ws_base;
    float* ws_off = (float*)(ws_base + sz_v);
    k_vgemv8<<<(BM + 7) / 8, 256, 0, stream>>>(value, W_v, b_v, ws_v, BM, flag);
    k_vgemv8<<<(BN + 7) / 8, 256, 0, stream>>>(query, W_off, b_off, ws_off, BN, flag);
    k_fused<float><<<BN, 256, 0, stream>>>(query, ref_points, ws_off,
                                           W_attn, b_attn, ws_v, d_out, N, BN, flag);
  } else {
    bf16* ws_v = (bf16*)ws_base;
    k_value_proj<bf16><<<BM, 256, 0, stream>>>(value, W_v, b_v, ws_v, BM, flag);
    k_fused_fb<bf16><<<BN, 256, 0, stream>>>(query, ref_points, W_off, b_off,
                                             W_attn, b_attn, ws_v, d_out, N, BN, flag);
  }
}

// Round 6
// 352.660 us; speedup vs baseline: 1.5814x; 1.1352x over previous
//
#include <hip/hip_runtime.h>
#include <hip/hip_bf16.h>

// DeformableAttention3D — MI355X (gfx950)
// R13: R12 postmortem revealed inputs are F32 (flag==0 path ran). No fp32 MFMA
// on CDNA4 -> use split-bf16: a = hi+lo, a*w ~= hi*wh + hi*wl + lo*wh (3 MFMAs,
// ~2^-17 rel err). A split on-the-fly in registers; W pre-split+transposed once
// (k_wsplit_all, 768KB ws). Projections move from 157TF VALU to 2.5PF matrix.
//   * k_mfma_projf: f32-A split-bf16 GEMM, 4 waves/block, wave tile 32x64,
//     16x16x32_bf16; layouts A row=l&15,k=(l>>4)*8+j; C col=l&15,row=(l>>4)*4+r.
//   * bf16-input path (flag==1) kept from R12 (k_transpose_bf16 + k_mfma_proj).
//   * k_fused2 / lower tiers verbatim.
#define EMBED    256
#define HEADS    8
#define LEVELS   4
#define POINTS   4
#define BATCH    2
#define M_TOT    21760   // 128*128 + 64*64 + 32*32 + 16*16
#define LDP      (EMBED + 4)   // padded LDS leading dim

typedef __hip_bfloat16 bf16;
typedef __attribute__((ext_vector_type(8))) short short8;
typedef __attribute__((ext_vector_type(8))) short bf16x8s;  // 8 bf16 (4 VGPRs)
typedef __attribute__((ext_vector_type(4))) float f32x4;

__device__ __constant__ int c_H[LEVELS]  = {128, 64, 32, 16};
__device__ __constant__ int c_St[LEVELS] = {0, 16384, 20480, 21504};

template<bool BF>
__device__ __forceinline__ float ldf(const void* p, size_t i) {
  if (BF) return __bfloat162float(((const bf16*)p)[i]);
  else    return ((const float*)p)[i];
}
__device__ __forceinline__ float vt2f(float x) { return x; }
__device__ __forceinline__ float vt2f(bf16 x)  { return __bfloat162float(x); }

template<bool BF>
__device__ __forceinline__ float4 ld4(const void* p, size_t i) {
  if (BF) {
    ushort4 u = *(const ushort4*)((const bf16*)p + i);
    float4 f;
    f.x = __bfloat162float(*reinterpret_cast<bf16*>(&u.x));
    f.y = __bfloat162float(*reinterpret_cast<bf16*>(&u.y));
    f.z = __bfloat162float(*reinterpret_cast<bf16*>(&u.z));
    f.w = __bfloat162float(*reinterpret_cast<bf16*>(&u.w));
    return f;
  } else {
    return *(const float4*)((const float*)p + i);
  }
}

__device__ __forceinline__ void fma4(float4& ac, float s, const float4& wv) {
  ac.x = fmaf(s, wv.x, ac.x);
  ac.y = fmaf(s, wv.y, ac.y);
  ac.z = fmaf(s, wv.z, ac.z);
  ac.w = fmaf(s, wv.w, ac.w);
}

// split 8 f32 -> hi/lo bf16x8 (in registers)
__device__ __forceinline__ void split8(const float4 x, const float4 y,
                                       bf16x8s& h, bf16x8s& l) {
  float f[8] = {x.x, x.y, x.z, x.w, y.x, y.y, y.z, y.w};
#pragma unroll
  for (int j = 0; j < 8; ++j) {
    bf16 hb = __float2bfloat16(f[j]);
    float r = f[j] - __bfloat162float(hb);
    bf16 lb = __float2bfloat16(r);
    h[j] = *reinterpret_cast<short*>(&hb);
    l[j] = *reinterpret_cast<short*>(&lb);
  }
}

// ---------------------------------------------------------------------------
// Dtype detector (flag=1 -> buffers bf16, flag=0 -> f32). Verbatim.
// ---------------------------------------------------------------------------
__global__ __launch_bounds__(256)
void k_detect(const unsigned short* __restrict__ q16, int* __restrict__ flag) {
  __shared__ int cnt;
  if (threadIdx.x == 0) cnt = 0;
  __syncthreads();
  int c = 0;
  for (int i = threadIdx.x; i < 8192; i += 256) {
    unsigned short v = q16[i];
    if ((v & 0x7F80u) == 0x7F80u) ++c;   // bf16 Inf/NaN pattern
  }
  if (c) atomicAdd(&cnt, c);
  __syncthreads();
  if (threadIdx.x == 0) flag[0] = (cnt == 0) ? 1 : 0;
}

// ---------------------------------------------------------------------------
// bf16 path (flag==1): transpose  WT[N][K] = W[K][N].  Verbatim R12.
// ---------------------------------------------------------------------------
__global__ __launch_bounds__(256)
void k_transpose_bf16(const unsigned short* __restrict__ W,
                      unsigned short* __restrict__ WT,
                      int K, int N, const int* __restrict__ flag) {
  if (*flag != 1) return;
  __shared__ unsigned short tile[64][65];
  const int ntn = N >> 6;
  const int tk = (int)blockIdx.x / ntn;
  const int tn = (int)blockIdx.x % ntn;
  const int k0 = tk << 6, n0 = tn << 6;
  const int t   = threadIdx.x;
  const int row = t >> 2;            // 0..63
  const int cq  = (t & 3) << 4;      // 0,16,32,48
  const unsigned short* src = W + (size_t)(k0 + row) * N + n0 + cq;
#pragma unroll
  for (int j = 0; j < 16; ++j) tile[row][cq + j] = src[j];
  __syncthreads();
  unsigned short* dst = WT + (size_t)(n0 + row) * K + k0 + cq;
#pragma unroll
  for (int j = 0; j < 16; ++j) dst[j] = tile[cq + j][row];
}

// ---------------------------------------------------------------------------
// f32 path (flag==0): all three W's -> transposed hi/lo bf16 in one launch.
// bid<16: W_v (256x256); <32: W_off (256x256); else: W_attn (256x128).
// ---------------------------------------------------------------------------
__global__ __launch_bounds__(256)
void k_wsplit_all(const float* __restrict__ Wv, const float* __restrict__ Woff,
                  const float* __restrict__ Wattn,
                  bf16* __restrict__ Tvh, bf16* __restrict__ Tvl,
                  bf16* __restrict__ Toh, bf16* __restrict__ Tol,
                  bf16* __restrict__ Tah, bf16* __restrict__ Tal,
                  const int* __restrict__ flag) {
  if (*flag != 0) return;
  int bid = (int)blockIdx.x;
  const float* W; bf16 *H, *L; int N;
  if (bid < 16)      { W = Wv;    H = Tvh; L = Tvl; N = 256; }
  else if (bid < 32) { W = Woff;  H = Toh; L = Tol; N = 256; bid -= 16; }
  else               { W = Wattn; H = Tah; L = Tal; N = 128; bid -= 32; }
  const int K = 256;
  __shared__ float tile[64][65];
  const int ntn = N >> 6;
  const int tk = bid / ntn, tn = bid % ntn;
  const int k0 = tk << 6, n0 = tn << 6;
  const int t   = threadIdx.x;
  const int row = t >> 2;            // 0..63
  const int cq  = (t & 3) << 4;      // 0,16,32,48
  const float* src = W + (size_t)(k0 + row) * N + n0 + cq;
#pragma unroll
  for (int j = 0; j < 16; ++j) tile[row][cq + j] = src[j];
  __syncthreads();
  const size_t d0 = (size_t)(n0 + row) * K + k0 + cq;
#pragma unroll
  for (int j = 0; j < 16; ++j) {
    float v = tile[cq + j][row];
    bf16 hb = __float2bfloat16(v);
    float r = v - __bfloat162float(hb);
    H[d0 + j] = hb;
    L[d0 + j] = __float2bfloat16(r);
  }
}

// ---------------------------------------------------------------------------
// bf16-input MFMA projection (flag==1). Verbatim R12.
// ---------------------------------------------------------------------------
__global__ __launch_bounds__(256)
void k_mfma_proj(const bf16* __restrict__ A, const bf16* __restrict__ WT,
                 const void* __restrict__ bias, float* __restrict__ C,
                 int M, int N, const int* __restrict__ flag) {
  if (*flag != 1) return;
  const int colBlocks = N >> 7;
  const int rb = (int)blockIdx.x / colBlocks;
  const int cb = (int)blockIdx.x % colBlocks;
  const int t   = threadIdx.x;
  const int wid = t >> 6;
  const int l   = t & 63;
  const int lrow = l & 15;
  const int lk8  = (l >> 4) << 3;
  const int r0 = rb * 64 + (wid & 1) * 32;
  const int c0 = cb * 128 + (wid >> 1) * 64;

  f32x4 acc[2][4];
#pragma unroll
  for (int rf = 0; rf < 2; ++rf)
#pragma unroll
    for (int cf = 0; cf < 4; ++cf) acc[rf][cf] = (f32x4){0.f, 0.f, 0.f, 0.f};

  const bf16* Ap0 = A + (size_t)min(r0 + lrow,      M - 1) * EMBED + lk8;
  const bf16* Ap1 = A + (size_t)min(r0 + 16 + lrow, M - 1) * EMBED + lk8;
  const bf16* Bp  = WT + (size_t)(c0 + lrow) * EMBED + lk8;

#pragma unroll
  for (int k = 0; k < EMBED; k += 32) {
    bf16x8s a0 = *(const bf16x8s*)(Ap0 + k);
    bf16x8s a1 = *(const bf16x8s*)(Ap1 + k);
    bf16x8s b0 = *(const bf16x8s*)(Bp + 0 * 16 * EMBED + k);
    bf16x8s b1 = *(const bf16x8s*)(Bp + 1 * 16 * EMBED + k);
    bf16x8s b2 = *(const bf16x8s*)(Bp + 2 * 16 * EMBED + k);
    bf16x8s b3 = *(const bf16x8s*)(Bp + 3 * 16 * EMBED + k);
    acc[0][0] = __builtin_amdgcn_mfma_f32_16x16x32_bf16(a0, b0, acc[0][0], 0, 0, 0);
    acc[0][1] = __builtin_amdgcn_mfma_f32_16x16x32_bf16(a0, b1, acc[0][1], 0, 0, 0);
    acc[0][2] = __builtin_amdgcn_mfma_f32_16x16x32_bf16(a0, b2, acc[0][2], 0, 0, 0);
    acc[0][3] = __builtin_amdgcn_mfma_f32_16x16x32_bf16(a0, b3, acc[0][3], 0, 0, 0);
    acc[1][0] = __builtin_amdgcn_mfma_f32_16x16x32_bf16(a1, b0, acc[1][0], 0, 0, 0);
    acc[1][1] = __builtin_amdgcn_mfma_f32_16x16x32_bf16(a1, b1, acc[1][1], 0, 0, 0);
    acc[1][2] = __builtin_amdgcn_mfma_f32_16x16x32_bf16(a1, b2, acc[1][2], 0, 0, 0);
    acc[1][3] = __builtin_amdgcn_mfma_f32_16x16x32_bf16(a1, b3, acc[1][3], 0, 0, 0);
  }

  const int rbase = (l >> 4) << 2;
#pragma unroll
  for (int cf = 0; cf < 4; ++cf) {
    const int col = c0 + cf * 16 + lrow;
    const float bv = ldf<true>(bias, col);
#pragma unroll
    for (int rf = 0; rf < 2; ++rf) {
#pragma unroll
      for (int r = 0; r < 4; ++r) {
        const int row = r0 + rf * 16 + rbase + r;
        if (row < M) C[(size_t)row * N + col] = acc[rf][cf][r] + bv;
      }
    }
  }
}

// ---------------------------------------------------------------------------
// R13: f32-input split-bf16 MFMA projection (flag==0).
// C[MxN] = A[Mx256] @ W + bias; A split hi/lo on the fly; W pre-split (WThi/lo).
// Block = 4 waves; block tile 64x128; wave tile 32x64; 3 MFMAs per frag pair.
// ---------------------------------------------------------------------------
__global__ __launch_bounds__(256)
void k_mfma_projf(const float* __restrict__ A, const bf16* __restrict__ WThi,
                  const bf16* __restrict__ WTlo, const float* __restrict__ bias,
                  float* __restrict__ C, int M, int N,
                  const int* __restrict__ flag) {
  if (*flag != 0) return;
  const int colBlocks = N >> 7;
  const int rb = (int)blockIdx.x / colBlocks;
  const int cb = (int)blockIdx.x % colBlocks;
  const int t   = threadIdx.x;
  const int wid = t >> 6;
  const int l   = t & 63;
  const int lrow = l & 15;
  const int lk8  = (l >> 4) << 3;
  const int r0 = rb * 64 + (wid & 1) * 32;
  const int c0 = cb * 128 + (wid >> 1) * 64;

  f32x4 acc[2][4];
#pragma unroll
  for (int rf = 0; rf < 2; ++rf)
#pragma unroll
    for (int cf = 0; cf < 4; ++cf) acc[rf][cf] = (f32x4){0.f, 0.f, 0.f, 0.f};

  const float* Ap0 = A + (size_t)min(r0 + lrow,      M - 1) * EMBED + lk8;
  const float* Ap1 = A + (size_t)min(r0 + 16 + lrow, M - 1) * EMBED + lk8;
  const bf16* Bh = WThi + (size_t)(c0 + lrow) * EMBED + lk8;
  const bf16* Bl = WTlo + (size_t)(c0 + lrow) * EMBED + lk8;

#pragma unroll 2
  for (int k = 0; k < EMBED; k += 32) {
    bf16x8s a0h, a0l, a1h, a1l;
    split8(*(const float4*)(Ap0 + k), *(const float4*)(Ap0 + k + 4), a0h, a0l);
    split8(*(const float4*)(Ap1 + k), *(const float4*)(Ap1 + k + 4), a1h, a1l);
    bf16x8s bh0 = *(const bf16x8s*)(Bh + 0 * 16 * EMBED + k);
    bf16x8s bh1 = *(const bf16x8s*)(Bh + 1 * 16 * EMBED + k);
    bf16x8s bh2 = *(const bf16x8s*)(Bh + 2 * 16 * EMBED + k);
    bf16x8s bh3 = *(const bf16x8s*)(Bh + 3 * 16 * EMBED + k);
    bf16x8s bl0 = *(const bf16x8s*)(Bl + 0 * 16 * EMBED + k);
    bf16x8s bl1 = *(const bf16x8s*)(Bl + 1 * 16 * EMBED + k);
    bf16x8s bl2 = *(const bf16x8s*)(Bl + 2 * 16 * EMBED + k);
    bf16x8s bl3 = *(const bf16x8s*)(Bl + 3 * 16 * EMBED + k);
    // hi*hi
    acc[0][0] = __builtin_amdgcn_mfma_f32_16x16x32_bf16(a0h, bh0, acc[0][0], 0, 0, 0);
    acc[0][1] = __builtin_amdgcn_mfma_f32_16x16x32_bf16(a0h, bh1, acc[0][1], 0, 0, 0);
    acc[0][2] = __builtin_amdgcn_mfma_f32_16x16x32_bf16(a0h, bh2, acc[0][2], 0, 0, 0);
    acc[0][3] = __builtin_amdgcn_mfma_f32_16x16x32_bf16(a0h, bh3, acc[0][3], 0, 0, 0);
    acc[1][0] = __builtin_amdgcn_mfma_f32_16x16x32_bf16(a1h, bh0, acc[1][0], 0, 0, 0);
    acc[1][1] = __builtin_amdgcn_mfma_f32_16x16x32_bf16(a1h, bh1, acc[1][1], 0, 0, 0);
    acc[1][2] = __builtin_amdgcn_mfma_f32_16x16x32_bf16(a1h, bh2, acc[1][2], 0, 0, 0);
    acc[1][3] = __builtin_amdgcn_mfma_f32_16x16x32_bf16(a1h, bh3, acc[1][3], 0, 0, 0);
    // hi*lo
    acc[0][0] = __builtin_amdgcn_mfma_f32_16x16x32_bf16(a0h, bl0, acc[0][0], 0, 0, 0);
    acc[0][1] = __builtin_amdgcn_mfma_f32_16x16x32_bf16(a0h, bl1, acc[0][1], 0, 0, 0);
    acc[0][2] = __builtin_amdgcn_mfma_f32_16x16x32_bf16(a0h, bl2, acc[0][2], 0, 0, 0);
    acc[0][3] = __builtin_amdgcn_mfma_f32_16x16x32_bf16(a0h, bl3, acc[0][3], 0, 0, 0);
    acc[1][0] = __builtin_amdgcn_mfma_f32_16x16x32_bf16(a1h, bl0, acc[1][0], 0, 0, 0);
    acc[1][1] = __builtin_amdgcn_mfma_f32_16x16x32_bf16(a1h, bl1, acc[1][1], 0, 0, 0);
    acc[1][2] = __builtin_amdgcn_mfma_f32_16x16x32_bf16(a1h, bl2, acc[1][2], 0, 0, 0);
    acc[1][3] = __builtin_amdgcn_mfma_f32_16x16x32_bf16(a1h, bl3, acc[1][3], 0, 0, 0);
    // lo*hi
    acc[0][0] = __builtin_amdgcn_mfma_f32_16x16x32_bf16(a0l, bh0, acc[0][0], 0, 0, 0);
    acc[0][1] = __builtin_amdgcn_mfma_f32_16x16x32_bf16(a0l, bh1, acc[0][1], 0, 0, 0);
    acc[0][2] = __builtin_amdgcn_mfma_f32_16x16x32_bf16(a0l, bh2, acc[0][2], 0, 0, 0);
    acc[0][3] = __builtin_amdgcn_mfma_f32_16x16x32_bf16(a0l, bh3, acc[0][3], 0, 0, 0);
    acc[1][0] = __builtin_amdgcn_mfma_f32_16x16x32_bf16(a1l, bh0, acc[1][0], 0, 0, 0);
    acc[1][1] = __builtin_amdgcn_mfma_f32_16x16x32_bf16(a1l, bh1, acc[1][1], 0, 0, 0);
    acc[1][2] = __builtin_amdgcn_mfma_f32_16x16x32_bf16(a1l, bh2, acc[1][2], 0, 0, 0);
    acc[1][3] = __builtin_amdgcn_mfma_f32_16x16x32_bf16(a1l, bh3, acc[1][3], 0, 0, 0);
  }

  const int rbase = (l >> 4) << 2;
#pragma unroll
  for (int cf = 0; cf < 4; ++cf) {
    const int col = c0 + cf * 16 + lrow;
    const float bv = bias[col];
#pragma unroll
    for (int rf = 0; rf < 2; ++rf) {
#pragma unroll
      for (int r = 0; r < 4; ++r) {
        const int row = r0 + rf * 16 + rbase + r;
        if (row < M) C[(size_t)row * N + col] = acc[rf][cf][r] + bv;
      }
    }
  }
}

// ---------------------------------------------------------------------------
// shared staging: 16 rows of A (EMBED cols) into padded LDS tile (R11)
// ---------------------------------------------------------------------------
template<bool BF>
__device__ __forceinline__ void stage16(const void* __restrict__ A,
                                        float (*rowA)[LDP],
                                        int r0, int M, int t) {
  int r  = t >> 4;
  int rr = min(r0 + r, M - 1);
  int c0 = (t & 15) * 16;
  if (BF) {
    const bf16* ap = (const bf16*)A + (size_t)rr * EMBED + c0;
    short8 a0 = *(const short8*)ap;
    short8 a1 = *(const short8*)(ap + 8);
#pragma unroll
    for (int j = 0; j < 8; ++j) {
      short s0 = a0[j], s1 = a1[j];
      rowA[r][c0 + j]     = __bfloat162float(*reinterpret_cast<bf16*>(&s0));
      rowA[r][c0 + 8 + j] = __bfloat162float(*reinterpret_cast<bf16*>(&s1));
    }
  } else {
    const float* ap = (const float*)A + (size_t)rr * EMBED + c0;
#pragma unroll
    for (int j = 0; j < 4; ++j) {
      float4 f = *(const float4*)(ap + j * 4);
      rowA[r][c0 + j * 4 + 0] = f.x;
      rowA[r][c0 + j * 4 + 1] = f.y;
      rowA[r][c0 + j * 4 + 2] = f.z;
      rowA[r][c0 + j * 4 + 3] = f.w;
    }
  }
}

// ---------------------------------------------------------------------------
// R11 tier kernels (need_full fallback): 4x4 / 2x4 register-blocked GEMVs.
// ---------------------------------------------------------------------------
template<bool BF>
__device__ void vgemv4x4_body(const void* __restrict__ A, const void* __restrict__ W,
                              const void* __restrict__ bias, float* __restrict__ C,
                              int M) {
  const int t  = threadIdx.x;
  const int r0 = blockIdx.x * 16;
  if (r0 >= M) return;

  __shared__ float rowA[16][LDP];
  stage16<BF>(A, rowA, r0, M, t);
  __syncthreads();

  const int g  = t >> 6;
  const int c0 = (t & 63) * 4;

  float4 bv;
  bv.x = ldf<BF>(bias, c0 + 0);
  bv.y = ldf<BF>(bias, c0 + 1);
  bv.z = ldf<BF>(bias, c0 + 2);
  bv.w = ldf<BF>(bias, c0 + 3);

  float4 acc[4];
#pragma unroll
  for (int r = 0; r < 4; ++r) acc[r] = bv;

#pragma unroll 2
  for (int k = 0; k < EMBED; k += 4) {
    float4 av[4];
#pragma unroll
    for (int r = 0; r < 4; ++r)
      av[r] = *(const float4*)&rowA[g * 4 + r][k];
    float4 w0 = ld4<BF>(W, (size_t)(k + 0) * EMBED + c0);
    float4 w1 = ld4<BF>(W, (size_t)(k + 1) * EMBED + c0);
    float4 w2 = ld4<BF>(W, (size_t)(k + 2) * EMBED + c0);
    float4 w3 = ld4<BF>(W, (size_t)(k + 3) * EMBED + c0);
#pragma unroll
    for (int r = 0; r < 4; ++r) {
      fma4(acc[r], av[r].x, w0);
      fma4(acc[r], av[r].y, w1);
      fma4(acc[r], av[r].z, w2);
      fma4(acc[r], av[r].w, w3);
    }
  }
#pragma unroll
  for (int r = 0; r < 4; ++r) {
    int row = r0 + g * 4 + r;
    if (row < M) *(float4*)&C[(size_t)row * EMBED + c0] = acc[r];
  }
}

__global__ __launch_bounds__(256)
void k_vgemv4x4(const void* A, const void* W, const void* bias, float* C,
                int M, const int* flag) {
  if (*flag) vgemv4x4_body<true >(A, W, bias, C, M);
  else       vgemv4x4_body<false>(A, W, bias, C, M);
}

template<bool BF>
__device__ void agemv4_body(const void* __restrict__ A, const void* __restrict__ W,
                            const void* __restrict__ bias, float* __restrict__ C,
                            int M) {
  const int t  = threadIdx.x;
  const int r0 = blockIdx.x * 16;
  if (r0 >= M) return;

  __shared__ float rowA[16][LDP];
  stage16<BF>(A, rowA, r0, M, t);
  __syncthreads();

  const int g  = t >> 5;
  const int c0 = (t & 31) * 4;

  float4 bv;
  bv.x = ldf<BF>(bias, c0 + 0);
  bv.y = ldf<BF>(bias, c0 + 1);
  bv.z = ldf<BF>(bias, c0 + 2);
  bv.w = ldf<BF>(bias, c0 + 3);

  float4 acc[2];
  acc[0] = bv; acc[1] = bv;

#pragma unroll 2
  for (int k = 0; k < EMBED; k += 4) {
    float4 a0 = *(const float4*)&rowA[g * 2 + 0][k];
    float4 a1 = *(const float4*)&rowA[g * 2 + 1][k];
    float4 w0 = ld4<BF>(W, (size_t)(k + 0) * 128 + c0);
    float4 w1 = ld4<BF>(W, (size_t)(k + 1) * 128 + c0);
    float4 w2 = ld4<BF>(W, (size_t)(k + 2) * 128 + c0);
    float4 w3 = ld4<BF>(W, (size_t)(k + 3) * 128 + c0);
    fma4(acc[0], a0.x, w0); fma4(acc[0], a0.y, w1);
    fma4(acc[0], a0.z, w2); fma4(acc[0], a0.w, w3);
    fma4(acc[1], a1.x, w0); fma4(acc[1], a1.y, w1);
    fma4(acc[1], a1.z, w2); fma4(acc[1], a1.w, w3);
  }
#pragma unroll
  for (int r = 0; r < 2; ++r) {
    int row = r0 + g * 2 + r;
    if (row < M) *(float4*)&C[(size_t)row * 128 + c0] = acc[r];
  }
}

__global__ __launch_bounds__(256)
void k_agemv4(const void* A, const void* W, const void* bias, float* C,
              int M, const int* flag) {
  if (*flag) agemv4_body<true >(A, W, bias, C, M);
  else       agemv4_body<false>(A, W, bias, C, M);
}

// ---------------------------------------------------------------------------
// R9 k_fused2 (verbatim): softmax + pack (t<128) + ILP-batched gather.
// ---------------------------------------------------------------------------
template<bool BF>
__device__ void fused2_body(const void* __restrict__ ref_points,
                            const float* __restrict__ off_pre,
                            const float* __restrict__ scores,
                            const float* __restrict__ v,
                            void* __restrict__ out, int N, int BN) {
  int q = blockIdx.x;
  if (q >= BN) return;
  int b = q / N;
  int t = threadIdx.x;

  __shared__ float  s_aw[128];
  __shared__ float  s_rp[2];
  __shared__ int4   s_pi[128];   // corner element index (cell<<8)
  __shared__ float4 s_pw[128];   // wa * bilinear * valid

  if (t < 2)   s_rp[t] = ldf<BF>(ref_points, (size_t)q * 2 + t);
  if (t < 128) s_aw[t] = scores[(size_t)q * 128 + t];
  __syncthreads();

  if (t < 128) {
    int base = t & ~15;
    float mx = -1e30f;
#pragma unroll
    for (int i = 0; i < 16; ++i) mx = fmaxf(mx, s_aw[base + i]);
    float sum = 0.f;
#pragma unroll
    for (int i = 0; i < 16; ++i) sum += expf(s_aw[base + i] - mx);
    float wa = expf(s_aw[t] - mx) / sum;

    int   l  = (t >> 2) & 3;
    int   Wl = 128 >> l;                       // levels are square
    float fW = (float)Wl;
    int   st = (int)((65536u - (65536u >> (2 * l))) / 3u);  // level start
    float ox = off_pre[(size_t)q * EMBED + 2 * t]     - 0.5f;
    float oy = off_pre[(size_t)q * EMBED + 2 * t + 1] - 0.5f;
    float x = fmaf(s_rp[0], fW, ox);
    float y = fmaf(s_rp[1], fW, oy);
    float x0f = floorf(x), y0f = floorf(y);
    float lx = x - x0f, ly = y - y0f;
    int x0 = (int)x0f, y0 = (int)y0f;
    int x1 = x0 + 1,   y1 = y0 + 1;
    float w00 = wa * (1.f - lx) * (1.f - ly);
    float w01 = wa * lx * (1.f - ly);
    float w10 = wa * (1.f - lx) * ly;
    float w11 = wa * lx * ly;
    bool vx0 = (unsigned)x0 < (unsigned)Wl;
    bool vx1 = (unsigned)x1 < (unsigned)Wl;
    bool vy0 = (unsigned)y0 < (unsigned)Wl;
    bool vy1 = (unsigned)y1 < (unsigned)Wl;
    int xc0 = min(max(x0, 0), Wl - 1), xc1 = min(max(x1, 0), Wl - 1);
    int yc0 = min(max(y0, 0), Wl - 1), yc1 = min(max(y1, 0), Wl - 1);
    int r0i = st + yc0 * Wl;
    int r1i = st + yc1 * Wl;
    int4 pi; float4 pw;
    pi.x = (r0i + xc0) << 8;  pw.x = (vx0 && vy0) ? w00 : 0.f;
    pi.y = (r0i + xc1) << 8;  pw.y = (vx1 && vy0) ? w01 : 0.f;
    pi.z = (r1i + xc0) << 8;  pw.z = (vx0 && vy1) ? w10 : 0.f;
    pi.w = (r1i + xc1) << 8;  pw.w = (vx1 && vy1) ? w11 : 0.f;
    s_pi[t] = pi;
    s_pw[t] = pw;
  }
  __syncthreads();

  const float* vb = v + (size_t)b * (M_TOT * EMBED);
  const int cb = (t >> 5) << 4;            // h*16
  float o0 = 0.f, o1 = 0.f;
#pragma unroll
  for (int g = 0; g < 4; ++g) {
    const int c0 = cb + (g << 2);
    int4   iA = s_pi[c0 + 0], iB = s_pi[c0 + 1], iC = s_pi[c0 + 2], iD = s_pi[c0 + 3];
    float4 wA = s_pw[c0 + 0], wB = s_pw[c0 + 1], wC = s_pw[c0 + 2], wD = s_pw[c0 + 3];
    float gA0 = vb[iA.x + t], gA1 = vb[iA.y + t], gA2 = vb[iA.z + t], gA3 = vb[iA.w + t];
    float gB0 = vb[iB.x + t], gB1 = vb[iB.y + t], gB2 = vb[iB.z + t], gB3 = vb[iB.w + t];
    float gC0 = vb[iC.x + t], gC1 = vb[iC.y + t], gC2 = vb[iC.z + t], gC3 = vb[iC.w + t];
    float gD0 = vb[iD.x + t], gD1 = vb[iD.y + t], gD2 = vb[iD.z + t], gD3 = vb[iD.w + t];
    o0 = fmaf(wA.x, gA0, o0); o1 = fmaf(wA.y, gA1, o1);
    o0 = fmaf(wA.z, gA2, o0); o1 = fmaf(wA.w, gA3, o1);
    o0 = fmaf(wB.x, gB0, o0); o1 = fmaf(wB.y, gB1, o1);
    o0 = fmaf(wB.z, gB2, o0); o1 = fmaf(wB.w, gB3, o1);
    o0 = fmaf(wC.x, gC0, o0); o1 = fmaf(wC.y, gC1, o1);
    o0 = fmaf(wC.z, gC2, o0); o1 = fmaf(wC.w, gC3, o1);
    o0 = fmaf(wD.x, gD0, o0); o1 = fmaf(wD.y, gD1, o1);
    o0 = fmaf(wD.z, gD2, o0); o1 = fmaf(wD.w, gD3, o1);
  }
  float o = o0 + o1;
  if (BF) ((bf16*)out)[(size_t)q * EMBED + t] = __float2bfloat16(o);
  else    ((float*)out)[(size_t)q * EMBED + t] = o;
}

__global__ __launch_bounds__(256)
void k_fused2(const void* ref_points, const float* off_pre, const float* scores,
              const float* v, void* out, int N, int BN, const int* flag) {
  if (*flag) fused2_body<true >(ref_points, off_pre, scores, v, out, N, BN);
  else       fused2_body<false>(ref_points, off_pre, scores, v, out, N, BN);
}

// ---------------------------------------------------------------------------
// MID TIER (R8, proven): 8-row GEMV + fused with in-kernel attn GEMV.
// ---------------------------------------------------------------------------
template<bool BF>
__device__ void vgemv8_body(const void* __restrict__ A, const void* __restrict__ W,
                            const void* __restrict__ bias, float* __restrict__ C,
                            int M) {
  const int t  = threadIdx.x;
  const int r0 = blockIdx.x * 8;
  if (r0 >= M) return;

  __shared__ float rowA[8][EMBED];
  {
    int r  = t >> 5;
    int rr = min(r0 + r, M - 1);
    int c0 = (t & 31) * 8;
    if (BF) {
      const bf16* ap = (const bf16*)A + (size_t)rr * EMBED + c0;
      short8 a = *(const short8*)ap;
#pragma unroll
      for (int j = 0; j < 8; ++j) {
        short s = a[j];
        bf16 hb = *reinterpret_cast<bf16*>(&s);
        rowA[r][c0 + j] = __bfloat162float(hb);
      }
    } else {
      const float* ap = (const float*)A + (size_t)rr * EMBED + c0;
#pragma unroll
      for (int j = 0; j < 8; ++j) rowA[r][c0 + j] = ap[j];
    }
  }
  __syncthreads();

  const int n = t;
  const float b = ldf<BF>(bias, n);
  float acc[8];
#pragma unroll
  for (int r = 0; r < 8; ++r) acc[r] = b;
#pragma unroll 4
  for (int k = 0; k < EMBED; ++k) {
    float w = ldf<BF>(W, (size_t)k * EMBED + n);
#pragma unroll
    for (int r = 0; r < 8; ++r) acc[r] = fmaf(rowA[r][k], w, acc[r]);
  }
#pragma unroll
  for (int r = 0; r < 8; ++r)
    if (r0 + r < M) C[(size_t)(r0 + r) * EMBED + n] = acc[r];
}

__global__ __launch_bounds__(256)
void k_vgemv8(const void* A, const void* W, const void* bias, float* C,
              int M, const int* flag) {
  if (*flag) vgemv8_body<true >(A, W, bias, C, M);
  else       vgemv8_body<false>(A, W, bias, C, M);
}

template<bool BF, class VT>
__device__ void fused_body(const void* __restrict__ query,
                           const void* __restrict__ ref_points,
                           const float* __restrict__ off_pre,
                           const void* __restrict__ W_attn,
                           const void* __restrict__ b_attn,
                           const VT* __restrict__ v,
                           void* __restrict__ out, int N, int BN) {
  int q = blockIdx.x;
  if (q >= BN) return;
  int b = q / N;
  int t = threadIdx.x;

  __shared__ float  row[EMBED];
  __shared__ float  s_part[256];
  __shared__ float  s_aw[HEADS * LEVELS * POINTS];
  __shared__ float  s_rp[2];
  __shared__ int4   s_pi[HEADS * LEVELS * POINTS];
  __shared__ float4 s_pw[HEADS * LEVELS * POINTS];

  row[t] = ldf<BF>(query, (size_t)q * EMBED + t);
  if (t < 2) s_rp[t] = ldf<BF>(ref_points, (size_t)q * 2 + t);
  __syncthreads();

  {
    const int col = t & 127;
    const int e0  = (t >> 7) * 128;
    float acc = 0.f;
#pragma unroll 8
    for (int e = 0; e < 128; ++e)
      acc = fmaf(row[e0 + e], ldf<BF>(W_attn, (size_t)(e0 + e) * 128 + col), acc);
    s_part[t] = acc;
  }
  __syncthreads();
  if (t < 128)
    s_aw[t] = ldf<BF>(b_attn, t) + s_part[t] + s_part[t + 128];
  __syncthreads();

  if (t < 128) {
    int base = t & ~15;
    float mx = -1e30f;
#pragma unroll
    for (int i = 0; i < 16; ++i) mx = fmaxf(mx, s_aw[base + i]);
    float sum = 0.f;
#pragma unroll
    for (int i = 0; i < 16; ++i) sum += expf(s_aw[base + i] - mx);
    float wa = expf(s_aw[t] - mx) / sum;

    int   l  = (t >> 2) & 3;
    int   Wl = 128 >> l;
    float fW = (float)Wl;
    int   st = (int)((65536u - (65536u >> (2 * l))) / 3u);
    float ox = off_pre[(size_t)q * EMBED + 2 * t]     - 0.5f;
    float oy = off_pre[(size_t)q * EMBED + 2 * t + 1] - 0.5f;
    float x = fmaf(s_rp[0], fW, ox);
    float y = fmaf(s_rp[1], fW, oy);
    float x0f = floorf(x), y0f = floorf(y);
    float lx = x - x0f, ly = y - y0f;
    int x0 = (int)x0f, y0 = (int)y0f;
    int x1 = x0 + 1,   y1 = y0 + 1;
    float w00 = wa * (1.f - lx) * (1.f - ly);
    float w01 = wa * lx * (1.f - ly);
    float w10 = wa * (1.f - lx) * ly;
    float w11 = wa * lx * ly;
    bool vx0 = (unsigned)x0 < (unsigned)Wl;
    bool vx1 = (unsigned)x1 < (unsigned)Wl;
    bool vy0 = (unsigned)y0 < (unsigned)Wl;
    bool vy1 = (unsigned)y1 < (unsigned)Wl;
    int xc0 = min(max(x0, 0), Wl - 1), xc1 = min(max(x1, 0), Wl - 1);
    int yc0 = min(max(y0, 0), Wl - 1), yc1 = min(max(y1, 0), Wl - 1);
    int r0i = st + yc0 * Wl;
    int r1i = st + yc1 * Wl;
    int4 pi; float4 pw;
    pi.x = (r0i + xc0) << 8;  pw.x = (vx0 && vy0) ? w00 : 0.f;
    pi.y = (r0i + xc1) << 8;  pw.y = (vx1 && vy0) ? w01 : 0.f;
    pi.z = (r1i + xc0) << 8;  pw.z = (vx0 && vy1) ? w10 : 0.f;
    pi.w = (r1i + xc1) << 8;  pw.w = (vx1 && vy1) ? w11 : 0.f;
    s_pi[t] = pi;
    s_pw[t] = pw;
  }
  __syncthreads();

  const int h = t >> 5;
  const VT* vbt = v + (size_t)b * M_TOT * EMBED + t;
  float o = 0.f;
#pragma unroll
  for (int lp = 0; lp < 16; ++lp) {
    int c = (h << 4) + lp;
    int4   i4 = s_pi[c];
    float4 w4 = s_pw[c];
    o = fmaf(w4.x, vt2f(vbt[i4.x]), o);
    o = fmaf(w4.y, vt2f(vbt[i4.y]), o);
    o = fmaf(w4.z, vt2f(vbt[i4.z]), o);
    o = fmaf(w4.w, vt2f(vbt[i4.w]), o);
  }
  if (BF) ((bf16*)out)[(size_t)q * EMBED + t] = __float2bfloat16(o);
  else    ((float*)out)[(size_t)q * EMBED + t] = o;
}

template<class VT>
__global__ __launch_bounds__(256)
void k_fused(const void* query, const void* ref_points, const float* off_pre,
             const void* W_attn, const void* b_attn,
             const VT* v, void* out, int N, int BN, const int* flag) {
  if (*flag) fused_body<true,  VT>(query, ref_points, off_pre, W_attn, b_attn, v, out, N, BN);
  else       fused_body<false, VT>(query, ref_points, off_pre, W_attn, b_attn, v, out, N, BN);
}

// ---------------------------------------------------------------------------
// Fallback path (ws too small): R2/R6's bf16 fused path, fully self-contained.
// ---------------------------------------------------------------------------
template<bool BF, class VT>
__device__ void vproj_body(const void* __restrict__ value,
                           const void* __restrict__ W_v,
                           const void* __restrict__ b_v,
                           VT* __restrict__ v, int BM) {
  int m = blockIdx.x;
  if (m >= BM) return;
  int t = threadIdx.x;
  __shared__ float row[EMBED];
  row[t] = ldf<BF>(value, (size_t)m * EMBED + t);
  __syncthreads();
  float acc = ldf<BF>(b_v, t);
#pragma unroll 8
  for (int e = 0; e < EMBED; ++e)
    acc = fmaf(row[e], ldf<BF>(W_v, (size_t)e * EMBED + t), acc);
  if (sizeof(VT) == 2) ((bf16*)v)[(size_t)m * EMBED + t] = __float2bfloat16(acc);
  else                 ((float*)v)[(size_t)m * EMBED + t] = acc;
}

template<class VT>
__global__ __launch_bounds__(256)
void k_value_proj(const void* value, const void* W_v, const void* b_v,
                  VT* v, int BM, const int* flag) {
  if (*flag) vproj_body<true,  VT>(value, W_v, b_v, v, BM);
  else       vproj_body<false, VT>(value, W_v, b_v, v, BM);
}

template<bool BF, class VT>
__device__ void fusedfb_body(const void* __restrict__ query,
                             const void* __restrict__ ref_points,
                             const void* __restrict__ W_off,
                             const void* __restrict__ b_off,
                             const void* __restrict__ W_attn,
                             const void* __restrict__ b_attn,
                             const VT* __restrict__ v,
                             void* __restrict__ out, int N, int BN) {
  int q = blockIdx.x;
  if (q >= BN) return;
  int b = q / N;
  int t = threadIdx.x;

  __shared__ float row[EMBED];
  __shared__ float s_off[EMBED];
  __shared__ float s_aw[HEADS * LEVELS * POINTS];
  __shared__ float s_rp[2];

  row[t] = ldf<BF>(query, (size_t)q * EMBED + t);
  if (t < 2) s_rp[t] = ldf<BF>(ref_points, (size_t)q * 2 + t);
  __syncthreads();

  {
    float acc = ldf<BF>(b_off, t);
#pragma unroll 8
    for (int e = 0; e < EMBED; ++e)
      acc = fmaf(row[e], ldf<BF>(W_off, (size_t)e * EMBED + t), acc);
    s_off[t] = acc;
  }
  if (t < 128) {
    float acc = ldf<BF>(b_attn, t);
#pragma unroll 8
    for (int e = 0; e < EMBED; ++e)
      acc = fmaf(row[e], ldf<BF>(W_attn, (size_t)e * 128 + t), acc);
    s_aw[t] = acc;
  }
  __syncthreads();

  float aval = 0.f;
  if (t < 128) {
    int base = t & ~15;
    float mx = -1e30f;
#pragma unroll
    for (int i = 0; i < 16; ++i) mx = fmaxf(mx, s_aw[base + i]);
    float sum = 0.f;
#pragma unroll
    for (int i = 0; i < 16; ++i) sum += expf(s_aw[base + i] - mx);
    aval = expf(s_aw[t] - mx) / sum;
  }
  __syncthreads();
  if (t < 128) s_aw[t] = aval;
  __syncthreads();

  int h = t >> 5;
  const VT* vb = v + (size_t)b * M_TOT * EMBED;
  float o = 0.f;
#pragma unroll
  for (int l = 0; l < LEVELS; ++l) {
    const int Hl = c_H[l], Wl = c_H[l];
    const VT* vl = vb + (size_t)c_St[l] * EMBED;
    const float fW = (float)Wl, fH = (float)Hl;
#pragma unroll
    for (int p = 0; p < POINTS; ++p) {
      int oi = ((h * LEVELS + l) * POINTS + p) << 1;
      float x = (s_rp[0] + s_off[oi]     / fW) * fW - 0.5f;
      float y = (s_rp[1] + s_off[oi + 1] / fH) * fH - 0.5f;
      float x0f = floorf(x), y0f = floorf(y);
      float lx = x - x0f, ly = y - y0f;
      int x0 = (int)x0f, y0 = (int)y0f;
      float wa = s_aw[(h * LEVELS + l) * POINTS + p];
      float cw[4] = {(1.f - lx) * (1.f - ly), lx * (1.f - ly),
                     (1.f - lx) * ly,         lx * ly};
      const int dxs[4] = {0, 1, 0, 1};
      const int dys[4] = {0, 0, 1, 1};
#pragma unroll
      for (int cidx = 0; cidx < 4; ++cidx) {
        int xi = x0 + dxs[cidx];
        int yi = y0 + dys[cidx];
        bool valid = (xi >= 0) & (xi < Wl) & (yi >= 0) & (yi < Hl);
        int xc = min(max(xi, 0), Wl - 1);
        int yc = min(max(yi, 0), Hl - 1);
        float g = vt2f(vl[(size_t)(yc * Wl + xc) * EMBED + t]);
        o += (valid ? wa * cw[cidx] : 0.f) * g;
      }
    }
  }
  if (BF) ((bf16*)out)[(size_t)q * EMBED + t] = __float2bfloat16(o);
  else    ((float*)out)[(size_t)q * EMBED + t] = o;
}

template<class VT>
__global__ __launch_bounds__(256)
void k_fused_fb(const void* query, const void* ref_points,
                const void* W_off, const void* b_off,
                const void* W_attn, const void* b_attn,
                const VT* v, void* out, int N, int BN, const int* flag) {
  if (*flag) fusedfb_body<true,  VT>(query, ref_points, W_off, b_off, W_attn, b_attn, v, out, N, BN);
  else       fusedfb_body<false, VT>(query, ref_points, W_off, b_off, W_attn, b_attn, v, out, N, BN);
}

// ---------------------------------------------------------------------------
extern "C" void kernel_launch(void* const* d_in, const int* in_sizes, int n_in,
                              void* d_out, int out_size, void* d_ws, size_t ws_size,
                              hipStream_t stream) {
  const void* query      = d_in[0];
  const void* value      = d_in[2];
  const void* ref_points = d_in[3];
  const void* W_off  = d_in[6];
  const void* b_off  = d_in[7];
  const void* W_attn = d_in[8];
  const void* b_attn = d_in[9];
  const void* W_v    = d_in[10];
  const void* b_v    = d_in[11];

  const int BN = in_sizes[0] / EMBED;   // 20000
  const int BM = in_sizes[2] / EMBED;   // 43520
  const int N  = BN / BATCH;

  int*  flag    = (int*)d_ws;
  char* ws_base = (char*)d_ws + 256;

  k_detect<<<1, 256, 0, stream>>>((const unsigned short*)query, flag);

  const size_t sz_v    = (size_t)BM * EMBED * sizeof(float);
  const size_t sz_off  = (size_t)BN * EMBED * sizeof(float);
  const size_t sz_attn = (size_t)BN * 128 * sizeof(float);
  // weight-transform area (union of bf16 path 320KB and f32 hi/lo path 640KB)
  const size_t sz_T    = (size_t)(256 * 256 * 2 + 256 * 128) * 2 /*hi+lo*/ * 2;
  const size_t need_mfma = 256 + sz_v + sz_off + sz_attn + sz_T;
  const size_t need_full = 256 + sz_v + sz_off + sz_attn;
  const size_t need_mid  = 256 + sz_v + sz_off;

  if (ws_size >= need_mfma) {
    float* ws_v    = (float*)ws_base;
    float* ws_off  = (float*)(ws_base + sz_v);
    float* ws_attn = (float*)(ws_base + sz_v + sz_off);
    unsigned short* wsT = (unsigned short*)(ws_base + sz_v + sz_off + sz_attn);
    // bf16 path layout
    unsigned short* wsT_v    = wsT;
    unsigned short* wsT_off  = wsT + 256 * 256;
    unsigned short* wsT_attn = wsT + 2 * 256 * 256;
    // f32 path layout (same area; only one path runs)
    bf16* Tvh = (bf16*)wsT;
    bf16* Tvl = Tvh + 256 * 256;
    bf16* Toh = Tvl + 256 * 256;
    bf16* Tol = Toh + 256 * 256;
    bf16* Tah = Tol + 256 * 256;
    bf16* Tal = Tah + 256 * 128;

    const int rbV = (BM + 63) / 64;   // 680
    const int rbQ = (BN + 63) / 64;   // 313

    // bf16 path (flag==1)
    k_transpose_bf16<<<16, 256, 0, stream>>>((const unsigned short*)W_v,    wsT_v,    256, 256, flag);
    k_transpose_bf16<<<16, 256, 0, stream>>>((const unsigned short*)W_off,  wsT_off,  256, 256, flag);
    k_transpose_bf16<<< 8, 256, 0, stream>>>((const unsigned short*)W_attn, wsT_attn, 256, 128, flag);
    k_mfma_proj<<<rbV * 2, 256, 0, stream>>>((const bf16*)value, (const bf16*)wsT_v,
                                             b_v, ws_v, BM, 256, flag);
    k_mfma_proj<<<rbQ * 2, 256, 0, stream>>>((const bf16*)query, (const bf16*)wsT_off,
                                             b_off, ws_off, BN, 256, flag);
    k_mfma_proj<<<rbQ,     256, 0, stream>>>((const bf16*)query, (const bf16*)wsT_attn,
                                             b_attn, ws_attn, BN, 128, flag);

    // f32 path (flag==0): split-bf16 MFMA
    k_wsplit_all<<<40, 256, 0, stream>>>((const float*)W_v, (const float*)W_off,
                                         (const float*)W_attn,
                                         Tvh, Tvl, Toh, Tol, Tah, Tal, flag);
    k_mfma_projf<<<rbV * 2, 256, 0, stream>>>((const float*)value, Tvh, Tvl,
                                              (const float*)b_v, ws_v, BM, 256, flag);
    k_mfma_projf<<<rbQ * 2, 256, 0, stream>>>((const float*)query, Toh, Tol,
                                              (const float*)b_off, ws_off, BN, 256, flag);
    k_mfma_projf<<<rbQ,     256, 0, stream>>>((const float*)query, Tah, Tal,
                                              (const float*)b_attn, ws_attn, BN, 128, flag);

    k_fused2<<<BN, 256, 0, stream>>>(ref_points, ws_off, ws_attn, ws_v,
                                     d_out, N, BN, flag);
  } else if (ws_size >= need_full) {
    float* ws_v    = (float*)ws_base;
    float* ws_off  = (float*)(ws_base + sz_v);
    float* ws_attn = (float*)(ws_base + sz_v + sz_off);
    k_vgemv4x4<<<(BM + 15) / 16, 256, 0, stream>>>(value, W_v, b_v, ws_v, BM, flag);
    k_vgemv4x4<<<(BN + 15) / 16, 256, 0, stream>>>(query, W_off, b_off, ws_off, BN, flag);
    k_agemv4<<<(BN + 15) / 16, 256, 0, stream>>>(query, W_attn, b_attn, ws_attn, BN, flag);
    k_fused2<<<BN, 256, 0, stream>>>(ref_points, ws_off, ws_attn, ws_v,
                                     d_out, N, BN, flag);
  } else if (ws_size >= need_mid) {
    float* ws_v   = (float*)ws_base;
    float* ws_off = (float*)(ws_base + sz_v);
    k_vgemv8<<<(BM + 7) / 8, 256, 0, stream>>>(value, W_v, b_v, ws_v, BM, flag);
    k_vgemv8<<<(BN + 7) / 8, 256, 0, stream>>>(query, W_off, b_off, ws_off, BN, flag);
    k_fused<float><<<BN, 256, 0, stream>>>(query, ref_points, ws_off,
                                           W_attn, b_attn, ws_v, d_out, N, BN, flag);
  } else {
    bf16* ws_v = (bf16*)ws_base;
    k_value_proj<bf16><<<BM, 256, 0, stream>>>(value, W_v, b_v, ws_v, BM, flag);
    k_fused_fb<bf16><<<BN, 256, 0, stream>>>(query, ref_points, W_off, b_off,
                                             W_attn, b_attn, ws_v, d_out, N, BN, flag);
  }
}